// Round 18
// baseline (244.189 us; speedup 1.0000x reference)
//
#include <hip/hip_runtime.h>

#define KDIM 64
#define NBPAD 512          // padded bucket-array size (NB = 274 here)
#define SCHUNK 2048        // records per bin_scatter block
#define CCHUNK 4096        // records per count block (front_fused role 3)
#define YSPLIT 8           // row sort segments per bucket

typedef __attribute__((ext_vector_type(8))) short short8v;   // 8 bf16 (4 VGPRs)
typedef __attribute__((ext_vector_type(4))) float f32x4;     // MFMA acc
typedef __attribute__((ext_vector_type(2))) float f32x2;     // fp8 cvt result

__device__ __forceinline__ float bf16u_to_f(unsigned short u) {
    return __uint_as_float(((unsigned)u) << 16);
}
__device__ __forceinline__ float bf16lo(unsigned u) {
    return __uint_as_float(u << 16);
}
__device__ __forceinline__ float bf16hi(unsigned u) {
    return __uint_as_float(u & 0xFFFF0000u);
}
__device__ __forceinline__ unsigned short f_to_bf16u(float f) {
    unsigned b = __float_as_uint(f);
    b += 0x7FFF + ((b >> 16) & 1);          // round-to-nearest-even
    return (unsigned short)(b >> 16);
}
__device__ __forceinline__ unsigned pack2bf16(float lo, float hi) {
    return ((unsigned)f_to_bf16u(lo)) | (((unsigned)f_to_bf16u(hi)) << 16);
}
__device__ __forceinline__ float sigmoidf_(float x) {
    return 1.f / (1.f + __expf(-x));
}

// Unified row space over the 4 concatenated edge lists:
// [0,S) students (ui1,ui0), [S,S+E) exercises (iu1,iu0).
__device__ __forceinline__ int dec_row(int e,
    const int* __restrict__ i1, const int* __restrict__ i0,
    const int* __restrict__ j1, const int* __restrict__ j0,
    int n1, int n0, int m1, int S_)
{
    if (e < n1) return i1[e];
    e -= n1;
    if (e < n0) return i0[e];
    e -= n0;
    if (e < m1) return S_ + j1[e];
    e -= m1;
    return S_ + j0[e];
}

__device__ __forceinline__ void dec_full(int e,
    const int* __restrict__ i1, const float* __restrict__ v1,
    const int* __restrict__ i0, const float* __restrict__ v0,
    const int* __restrict__ j1, const float* __restrict__ w1,
    const int* __restrict__ j0, const float* __restrict__ w0,
    int n1, int n0, int m1, int m0, int S_,
    unsigned& row, unsigned& pk)
{
    int col; float v;
    if (e < n1) { row = (unsigned)i1[e]; col = i1[n1 + e]; v = v1[e]; }
    else if (e < n1 + n0) { int le = e - n1; row = (unsigned)i0[le]; col = i0[n0 + le]; v = v0[le]; }
    else if (e < n1 + n0 + m1) { int le = e - n1 - n0; row = (unsigned)(S_ + j1[le]); col = j1[m1 + le]; v = w1[le]; }
    else { int le = e - n1 - n0 - m1; row = (unsigned)(S_ + j0[le]); col = j0[m0 + le]; v = w0[le]; }
    pk = ((unsigned)col << 16) | (unsigned)f_to_bf16u(v);
}

// -------- front_fused: [prep weights | embed MFMA | bucket count] — three
// independent roles by blockIdx range, NO cross-block sync.
__global__ __launch_bounds__(256) void front_fused(
    const float* __restrict__ stuW, const float* __restrict__ exerW,
    const float* __restrict__ knowW,
    const float* __restrict__ W1, const float* __restrict__ W2,
    const float* __restrict__ W3,
    const int* __restrict__ i1, const int* __restrict__ i0,
    const int* __restrict__ j1, const int* __restrict__ j0,
    int n1, int n0, int m1, int S_, int n_rows, int ntot, int NB,
    unsigned short* __restrict__ tab0,
    unsigned short* __restrict__ W1t, unsigned short* __restrict__ W2t,
    float* __restrict__ w3r,
    int* __restrict__ bktCnt,
    int nPrep, int nEmb)
{
    __shared__ int shmem[NBPAD];
    const int tid = threadIdx.x;
    int bx = blockIdx.x;

    // ---------------- role 1: weight prep (W1t/W2t/w3r) ----------------
    if (bx < nPrep) {
        int i = bx * 256 + tid;
        if (i < 256 * 64) {                     // W1t[n][k] = relu(W1[k][n])
            int n = i >> 6, k = i & 63;
            W1t[i] = f_to_bf16u(fmaxf(W1[k * 256 + n], 0.f));
            return;
        }
        int j = i - 256 * 64;
        if (j < 128 * 256) {                    // W2t[n][k] = relu(W2[k][n])
            int n = j >> 8, k = j & 255;
            W2t[j] = f_to_bf16u(fmaxf(W2[k * 128 + n], 0.f));
            return;
        }
        int l = j - 128 * 256;
        if (l < 128) w3r[l] = fmaxf(W3[l], 0.f);
        return;
    }
    bx -= nPrep;

    // ---------------- role 2: embed MFMA (64 rows/block) ----------------
    if (bx < nEmb) {
        const int w = tid >> 6, l = tid & 63;
        const int lr = l & 15, lg = l >> 4;
        const int r0 = bx * 64 + 16 * w;

        const int arow = min(r0 + lr, n_rows - 1);
        const float* a = (arow < S_) ? (stuW + (size_t)arow * KDIM)
                                     : (exerW + (size_t)(arow - S_) * KDIM);
        float4 v0 = *((const float4*)(a + lg * 8));
        float4 v1 = *((const float4*)(a + lg * 8 + 4));
        float4 v2 = *((const float4*)(a + 32 + lg * 8));
        float4 v3 = *((const float4*)(a + 32 + lg * 8 + 4));
        union { unsigned u[4]; short8v s; } A0, A1;
        A0.u[0] = pack2bf16(v0.x, v0.y); A0.u[1] = pack2bf16(v0.z, v0.w);
        A0.u[2] = pack2bf16(v1.x, v1.y); A0.u[3] = pack2bf16(v1.z, v1.w);
        A1.u[0] = pack2bf16(v2.x, v2.y); A1.u[1] = pack2bf16(v2.z, v2.w);
        A1.u[2] = pack2bf16(v3.x, v3.y); A1.u[3] = pack2bf16(v3.z, v3.w);

        #pragma unroll
        for (int n = 0; n < 4; ++n) {
            const float* kb = knowW + (size_t)(n * 16 + lr) * KDIM + lg * 8;
            float4 b0f = *(const float4*)kb;
            float4 b0g = *(const float4*)(kb + 4);
            float4 b1f = *(const float4*)(kb + 32);
            float4 b1g = *(const float4*)(kb + 36);
            union { unsigned u[4]; short8v s; } B0, B1;
            B0.u[0] = pack2bf16(b0f.x, b0f.y); B0.u[1] = pack2bf16(b0f.z, b0f.w);
            B0.u[2] = pack2bf16(b0g.x, b0g.y); B0.u[3] = pack2bf16(b0g.z, b0g.w);
            B1.u[0] = pack2bf16(b1f.x, b1f.y); B1.u[1] = pack2bf16(b1f.z, b1f.w);
            B1.u[2] = pack2bf16(b1g.x, b1g.y); B1.u[3] = pack2bf16(b1g.z, b1g.w);
            f32x4 acc = {0.f, 0.f, 0.f, 0.f};
            acc = __builtin_amdgcn_mfma_f32_16x16x32_bf16(A0.s, B0.s, acc, 0, 0, 0);
            acc = __builtin_amdgcn_mfma_f32_16x16x32_bf16(A1.s, B1.s, acc, 0, 0, 0);
            #pragma unroll
            for (int q = 0; q < 4; ++q) {
                int srow = r0 + lg * 4 + q;
                if (srow < n_rows)
                    tab0[(size_t)srow * KDIM + n * 16 + lr] = f_to_bf16u(sigmoidf_(acc[q]));
            }
        }
        return;
    }
    bx -= nEmb;

    // ---------------- role 3: bucket count (CCHUNK=4096 records/block) -----
    for (int i = tid; i < NBPAD; i += 256) shmem[i] = 0;
    __syncthreads();
    const int e0 = bx * CCHUNK;
    #pragma unroll
    for (int it = 0; it < 16; ++it) {
        int e = e0 + it * 256 + tid;
        if (e < ntot) atomicAdd(&shmem[dec_row(e, i1, i0, j1, j0, n1, n0, m1, S_) >> 8], 1);
    }
    __syncthreads();
    for (int b = tid; b < NB; b += 256)
        if (shmem[b]) atomicAdd(&bktCnt[b], shmem[b]);
}

// -------- exclusive scan of NB bucket counts -> bktBase (+ cursor copy gcurA)
__global__ __launch_bounds__(256) void scan_tiny(
    const int* __restrict__ bktCnt, int* __restrict__ bktBase,
    int* __restrict__ gcurA, int NB)
{
    __shared__ int s[NBPAD + 1];
    for (int i = threadIdx.x; i < NB; i += 256) s[i] = bktCnt[i];
    __syncthreads();
    if (threadIdx.x == 0) {
        int acc = 0;
        for (int b = 0; b < NB; ++b) { int c = s[b]; s[b] = acc; acc += c; }
        s[NB] = acc;
    }
    __syncthreads();
    for (int i = threadIdx.x; i <= NB; i += 256) bktBase[i] = s[i];
    for (int i = threadIdx.x; i < NB; i += 256) gcurA[i] = s[i];
}

// -------- binned scatter v4: SCHUNK=2048 (grid 2x, LDS 22 KB -> 7 blocks/CU),
// single LDS atomic per record (hist return value = slot), shfl 512-prefix.
__global__ __launch_bounds__(256) void bin_scatter(
    const int* __restrict__ i1, const float* __restrict__ v1,
    const int* __restrict__ i0, const float* __restrict__ v0,
    const int* __restrict__ j1, const float* __restrict__ w1,
    const int* __restrict__ j0, const float* __restrict__ w0,
    int n1, int n0, int m1, int m0, int S_,
    int* __restrict__ gcurA,
    unsigned* __restrict__ recPacked, unsigned char* __restrict__ recRow,
    int ntot, int NB)
{
    __shared__ int h[NBPAD], sstart[NBPAD], gdst[NBPAD];
    __shared__ int wsum[8];
    __shared__ unsigned stageP[SCHUNK];
    __shared__ unsigned stageG[SCHUNK];      // (bkt<<8)|rowLocal == unified row id
    const int tid = threadIdx.x;
    const int e0 = blockIdx.x * SCHUNK;

    for (int i = tid; i < NBPAD; i += 256) h[i] = 0;
    __syncthreads();

    unsigned rrow[8], rpk[8];
    unsigned short rslot[8];
    #pragma unroll
    for (int it = 0; it < 8; ++it) {
        int e = e0 + it * 256 + tid;
        if (e < ntot) {
            dec_full(e, i1, v1, i0, v0, j1, w1, j0, w0, n1, n0, m1, m0, S_,
                     rrow[it], rpk[it]);
            rslot[it] = (unsigned short)atomicAdd(&h[rrow[it] >> 8], 1);
        } else {
            rrow[it] = 0xFFFFFFFFu;
        }
    }
    __syncthreads();

    {   // exclusive prefix over 512 buckets: per-wave shfl scans, one exchange.
        const int wv = tid >> 6, ln = tid & 63;
        int v0h = h[tid];
        int v1h = h[tid + 256];
        int s0 = v0h, s1 = v1h;
        #pragma unroll
        for (int o = 1; o < 64; o <<= 1) {
            int t0 = __shfl_up(s0, o);
            int t1 = __shfl_up(s1, o);
            if (ln >= o) { s0 += t0; s1 += t1; }
        }
        if (ln == 63) { wsum[wv] = s0; wsum[4 + wv] = s1; }
        __syncthreads();
        int woff0 = 0, total0 = 0, woff1lo = 0;
        #pragma unroll
        for (int i = 0; i < 4; ++i) {
            int wl = wsum[i], wh = wsum[4 + i];
            total0 += wl;
            if (i < wv) { woff0 += wl; woff1lo += wh; }
        }
        int excl0 = woff0 + s0 - v0h;                 // exclusive prefix of h[tid]
        int excl1 = total0 + woff1lo + s1 - v1h;      // exclusive prefix of h[tid+256]
        sstart[tid] = excl0;
        sstart[tid + 256] = excl1;
        if (v0h > 0) gdst[tid] = atomicAdd(&gcurA[tid], v0h);
        if (tid + 256 < NB && v1h > 0) gdst[tid + 256] = atomicAdd(&gcurA[tid + 256], v1h);
    }
    __syncthreads();

    #pragma unroll
    for (int it = 0; it < 8; ++it) {
        if (rrow[it] != 0xFFFFFFFFu) {
            int slot = sstart[rrow[it] >> 8] + (int)rslot[it];   // no atomics
            stageP[slot] = rpk[it];
            stageG[slot] = rrow[it];
        }
    }
    __syncthreads();

    int cnt = ntot - e0; if (cnt > SCHUNK) cnt = SCHUNK;
    for (int i = tid; i < cnt; i += 256) {
        unsigned gr = stageG[i];
        int bkt = gr >> 8;
        int dst = gdst[bkt] + (i - sstart[bkt]);
        recPacked[dst] = stageP[i];
        recRow[dst]   = (unsigned char)(gr & 255u);
    }
}

// -------- row_hist: block (b,y) histograms ONLY its segment -> hseg[b][y][256].
__global__ __launch_bounds__(256) void row_hist(
    const unsigned char* __restrict__ recRow, const int* __restrict__ bktBase,
    int* __restrict__ hseg)
{
    __shared__ int h[256];
    const int b = blockIdx.x, y = blockIdx.y, tid = threadIdx.x;
    const int start = bktBase[b], end = bktBase[b + 1];
    const int seg = (end - start + YSPLIT - 1) / YSPLIT;
    int myS = start + y * seg;  if (myS > end) myS = end;
    int myE = myS + seg;        if (myE > end) myE = end;

    h[tid] = 0;
    __syncthreads();
    for (int i = myS + tid; i < myE; i += 256)
        atomicAdd(&h[(int)recRow[i]], 1);
    __syncthreads();
    hseg[((size_t)b * YSPLIT + y) * 256 + tid] = h[tid];
}

// -------- row_sort2: merge segment histograms, scan, scatter own segment.
__global__ __launch_bounds__(256) void row_sort2(
    const unsigned* __restrict__ recPacked, const unsigned char* __restrict__ recRow,
    const int* __restrict__ bktBase, const int* __restrict__ hseg,
    int* __restrict__ ptr, unsigned* __restrict__ edges, int n_rows, int NB)
{
    __shared__ int sc[256], cur[256];
    const int b = blockIdx.x, y = blockIdx.y, tid = threadIdx.x;
    const int r0 = b << 8;
    const int start = bktBase[b], end = bktBase[b + 1];
    const int seg = (end - start + YSPLIT - 1) / YSPLIT;
    int myS = start + y * seg;  if (myS > end) myS = end;
    int myE = myS + seg;        if (myE > end) myE = end;

    int ht = 0, hb = 0;
    const int* hsb = hseg + (size_t)b * YSPLIT * 256 + tid;
    #pragma unroll
    for (int yy = 0; yy < YSPLIT; ++yy) {
        int v = hsb[yy * 256];
        ht += v;
        hb += (yy < y) ? v : 0;
    }

    sc[tid] = ht;
    __syncthreads();
    for (int o = 1; o < 256; o <<= 1) {
        int add = (tid >= o) ? sc[tid - o] : 0;
        __syncthreads();
        sc[tid] += add;
        __syncthreads();
    }
    const int excl = sc[tid] - ht;

    if (y == 0) {
        int grow = r0 + tid;
        if (grow < n_rows) ptr[grow] = start + excl;
        if (b == NB - 1 && tid == 0) ptr[n_rows] = end;
    }
    cur[tid] = excl + hb;
    __syncthreads();

    for (int i = myS + tid; i < myE; i += 256) {
        unsigned pk = recPacked[i];
        int r = (int)recRow[i];
        int dst = start + atomicAdd(&cur[r], 1);
        edges[dst] = pk;
    }
}

// -------- to_fp8: tab0 (bf16) -> tab8 (fp8 e4m3), 16 elems/thread (vectorized).
__global__ __launch_bounds__(256) void to_fp8(
    const unsigned short* __restrict__ tab0, unsigned char* __restrict__ tab8, int n)
{
    int i = blockIdx.x * 256 + threadIdx.x;
    if (i * 16 >= n) return;
    uint4 a = ((const uint4*)tab0)[i * 2];
    uint4 b = ((const uint4*)tab0)[i * 2 + 1];
    uint4 o;
    int t;
    t = __builtin_amdgcn_cvt_pk_fp8_f32(bf16lo(a.x), bf16hi(a.x), 0, false);
    o.x = (unsigned)__builtin_amdgcn_cvt_pk_fp8_f32(bf16lo(a.y), bf16hi(a.y), t, true);
    t = __builtin_amdgcn_cvt_pk_fp8_f32(bf16lo(a.z), bf16hi(a.z), 0, false);
    o.y = (unsigned)__builtin_amdgcn_cvt_pk_fp8_f32(bf16lo(a.w), bf16hi(a.w), t, true);
    t = __builtin_amdgcn_cvt_pk_fp8_f32(bf16lo(b.x), bf16hi(b.x), 0, false);
    o.z = (unsigned)__builtin_amdgcn_cvt_pk_fp8_f32(bf16lo(b.y), bf16hi(b.y), t, true);
    t = __builtin_amdgcn_cvt_pk_fp8_f32(bf16lo(b.z), bf16hi(b.z), 0, false);
    o.w = (unsigned)__builtin_amdgcn_cvt_pk_fp8_f32(bf16lo(b.w), bf16hi(b.w), t, true);
    ((uint4*)tab8)[i] = o;
}

// -------- Pull SpMM v4: fp8 gather + packed f32x2 accumulation (v_pk_fma_f32).
__global__ __launch_bounds__(256) void pull_spmm(
    const unsigned short* __restrict__ tab0,
    const unsigned char* __restrict__ tab8,
    const int* __restrict__ ptr, const unsigned* __restrict__ edges,
    unsigned short* __restrict__ tabF, int S_, int n_rows)
{
    const int w = blockIdx.x * 4 + (threadIdx.x >> 6);
    if (w >= n_rows) return;
    const int lane = threadIdx.x & 63;
    const int g = lane >> 3;      // 8 edge-groups
    const int s = lane & 7;       // k-range 8s..8s+7

    const unsigned char* X8 = tab8 + ((w < S_) ? ((size_t)S_ << 6) : (size_t)0)
                                   + (size_t)s * 8;

    f32x2 acc2[4];
    #pragma unroll
    for (int i = 0; i < 4; ++i) acc2[i] = (f32x2){0.f, 0.f};

    int e = ptr[w];
    const int ee = ptr[w + 1];
    unsigned u = (e + lane < ee) ? edges[e + lane] : 0u;
    while (e < ee) {
        int m = ee - e; if (m > 64) m = 64;
        unsigned un = (e + 64 + lane < ee) ? edges[e + 64 + lane] : 0u;  // prefetch
        int iters = (m + 7) >> 3;
        #pragma unroll 4
        for (int jj = 0; jj < iters; ++jj) {
            unsigned uj = __shfl(u, jj * 8 + g);     // 0-word: col 0, val 0 -> harmless
            float v = __uint_as_float(uj << 16);     // low 16 = bf16 val
            f32x2 vv = {v, v};
            uint2 xv = *(const uint2*)(X8 + (((size_t)(uj >> 16)) << 6));
            acc2[0] = __builtin_amdgcn_cvt_pk_f32_fp8(xv.x, false) * vv + acc2[0];
            acc2[1] = __builtin_amdgcn_cvt_pk_f32_fp8(xv.x, true)  * vv + acc2[1];
            acc2[2] = __builtin_amdgcn_cvt_pk_f32_fp8(xv.y, false) * vv + acc2[2];
            acc2[3] = __builtin_amdgcn_cvt_pk_f32_fp8(xv.y, true)  * vv + acc2[3];
        }
        u = un;
        e += m;
    }

    #pragma unroll
    for (int i = 0; i < 4; ++i) {
        #pragma unroll
        for (int c = 0; c < 2; ++c) {
            acc2[i][c] += __shfl_xor(acc2[i][c], 8);
            acc2[i][c] += __shfl_xor(acc2[i][c], 16);
            acc2[i][c] += __shfl_xor(acc2[i][c], 32);
        }
    }

    if (g == 0) {
        const uint4 x0 = *(const uint4*)(tab0 + ((size_t)w << 6) + (size_t)s * 8);
        uint4 o;
        o.x = pack2bf16(acc2[0][0] + bf16lo(x0.x), acc2[0][1] + bf16hi(x0.x));
        o.y = pack2bf16(acc2[1][0] + bf16lo(x0.y), acc2[1][1] + bf16hi(x0.y));
        o.z = pack2bf16(acc2[2][0] + bf16lo(x0.z), acc2[2][1] + bf16hi(x0.z));
        o.w = pack2bf16(acc2[3][0] + bf16lo(x0.w), acc2[3][1] + bf16hi(x0.w));
        *(uint4*)(tabF + ((size_t)w << 6) + (size_t)s * 8) = o;
    }
}

// -------- MFMA tail: gather -> GEMM1(64x256x64) -> GEMM2(64x128x256) -> dot.
__global__ __launch_bounds__(256, 1) void tail_mlp(
    const unsigned short* __restrict__ tabF,
    const float* __restrict__ discW,
    const unsigned short* __restrict__ W1t, const float* __restrict__ b1,
    const unsigned short* __restrict__ W2t, const float* __restrict__ b2,
    const float* __restrict__ w3r, const float* __restrict__ b3,
    const float* __restrict__ kn, const int* __restrict__ stu_id,
    const int* __restrict__ exer_id, float* __restrict__ out, int S_, int B)
{
    __shared__ __align__(16) unsigned short xs_bf[64][72];   // 9.0 KB (pad: 2-way banks)
    __shared__ __align__(16) unsigned short h1s[64][264];    // 33.0 KB
    __shared__ __align__(16) unsigned short h2s[64][136];    // 17.0 KB
    __shared__ float b1s[256], b2s[128], w3s[128];
    const int tid = threadIdx.x;
    const int b0 = blockIdx.x * 64;

    b1s[tid] = b1[tid];
    if (tid < 128) { b2s[tid] = b2[tid]; w3s[tid] = w3r[tid]; }

    // ---- phase 0: x = disc*(stat-diff)/3*kn -> bf16 LDS tile (vectorized x4)
    #pragma unroll
    for (int i = 0; i < 4; ++i) {
        int e4 = (i * 256 + tid) * 4;
        int r = e4 >> 6, k0 = e4 & 63;
        int b = b0 + r;
        float4 x4 = make_float4(0.f, 0.f, 0.f, 0.f);
        if (b < B) {
            int sid = stu_id[b], eid = exer_id[b];
            float c = sigmoidf_(discW[eid]) * (1.f / 3.f);
            ushort4 st4 = *((const ushort4*)(tabF + (size_t)sid * 64 + k0));
            ushort4 df4 = *((const ushort4*)(tabF + ((size_t)(S_ + eid)) * 64 + k0));
            float4 kn4 = *((const float4*)(kn + (size_t)b * 64 + k0));
            x4.x = c * (bf16u_to_f(st4.x) - bf16u_to_f(df4.x)) * kn4.x;
            x4.y = c * (bf16u_to_f(st4.y) - bf16u_to_f(df4.y)) * kn4.y;
            x4.z = c * (bf16u_to_f(st4.z) - bf16u_to_f(df4.z)) * kn4.z;
            x4.w = c * (bf16u_to_f(st4.w) - bf16u_to_f(df4.w)) * kn4.w;
        }
        ushort4 xb;
        xb.x = f_to_bf16u(x4.x); xb.y = f_to_bf16u(x4.y);
        xb.z = f_to_bf16u(x4.z); xb.w = f_to_bf16u(x4.w);
        *((ushort4*)&xs_bf[r][k0]) = xb;
    }
    __syncthreads();

    const int w  = tid >> 6;
    const int l  = tid & 63;
    const int lr = l & 15;        // A row / B col / C col
    const int lg = l >> 4;        // k-group (8 contig k each)

    // ---- GEMM1: H1 = sigmoid(X[64x64] @ W1r[64x256] + b1)
    {
        short8v a0 = *(const short8v*)&xs_bf[16 * w + lr][lg * 8];
        short8v a1 = *(const short8v*)&xs_bf[16 * w + lr][32 + lg * 8];
        const unsigned short* w1base = W1t + (size_t)lr * 64 + lg * 8;
        #pragma unroll 4
        for (int n = 0; n < 16; ++n) {
            short8v bb0 = *(const short8v*)(w1base + n * 1024);
            short8v bb1 = *(const short8v*)(w1base + n * 1024 + 32);
            f32x4 acc = {0.f, 0.f, 0.f, 0.f};
            acc = __builtin_amdgcn_mfma_f32_16x16x32_bf16(a0, bb0, acc, 0, 0, 0);
            acc = __builtin_amdgcn_mfma_f32_16x16x32_bf16(a1, bb1, acc, 0, 0, 0);
            int col = n * 16 + lr;
            float bias = b1s[col];
            #pragma unroll
            for (int q = 0; q < 4; ++q)
                h1s[16 * w + lg * 4 + q][col] = f_to_bf16u(sigmoidf_(acc[q] + bias));
        }
    }
    __syncthreads();

    // ---- GEMM2: H2 = sigmoid(H1[64x256] @ W2r[256x128] + b2)
    {
        short8v ak[8];
        #pragma unroll
        for (int kk = 0; kk < 8; ++kk)
            ak[kk] = *(const short8v*)&h1s[16 * w + lr][kk * 32 + lg * 8];
        const unsigned short* w2base = W2t + (size_t)lr * 256 + lg * 8;
        #pragma unroll 2
        for (int n = 0; n < 8; ++n) {
            const unsigned short* bp = w2base + (size_t)n * 16 * 256;
            f32x4 acc = {0.f, 0.f, 0.f, 0.f};
            #pragma unroll
            for (int kk = 0; kk < 8; ++kk) {
                short8v bb = *(const short8v*)(bp + kk * 32);
                acc = __builtin_amdgcn_mfma_f32_16x16x32_bf16(ak[kk], bb, acc, 0, 0, 0);
            }
            int col = n * 16 + lr;
            float bias = b2s[col];
            #pragma unroll
            for (int q = 0; q < 4; ++q)
                h2s[16 * w + lg * 4 + q][col] = f_to_bf16u(sigmoidf_(acc[q] + bias));
        }
    }
    __syncthreads();

    // ---- GEMM3: out = sigmoid(H2 @ w3r + b3)   (64 rows, VALU)
    if (tid < 64) {
        int b = b0 + tid;
        if (b < B) {
            float acc = b3[0];
            const unsigned* h2r = (const unsigned*)&h2s[tid][0];
            #pragma unroll 8
            for (int jj = 0; jj < 64; ++jj) {
                unsigned hv = h2r[jj];
                acc += bf16lo(hv) * w3s[jj * 2 + 0] + bf16hi(hv) * w3s[jj * 2 + 1];
            }
            out[b] = sigmoidf_(acc);
        }
    }
}

extern "C" void kernel_launch(void* const* d_in, const int* in_sizes, int n_in,
                              void* d_out, int out_size, void* d_ws, size_t ws_size,
                              hipStream_t stream) {
    const float* stuW  = (const float*)d_in[0];
    const float* exerW = (const float*)d_in[1];
    const float* knowW = (const float*)d_in[2];
    const float* discW = (const float*)d_in[3];
    const float* W1 = (const float*)d_in[4];
    const float* b1 = (const float*)d_in[5];
    const float* W2 = (const float*)d_in[6];
    const float* b2 = (const float*)d_in[7];
    const float* W3 = (const float*)d_in[8];
    const float* b3 = (const float*)d_in[9];
    const int*   ui1_idx = (const int*)d_in[10];
    const float* ui1_val = (const float*)d_in[11];
    const int*   ui0_idx = (const int*)d_in[12];
    const float* ui0_val = (const float*)d_in[13];
    const int*   iu1_idx = (const int*)d_in[14];
    const float* iu1_val = (const float*)d_in[15];
    const int*   iu0_idx = (const int*)d_in[16];
    const float* iu0_val = (const float*)d_in[17];
    const float* kn      = (const float*)d_in[18];
    const int*   stu_id  = (const int*)d_in[19];
    const int*   exer_id = (const int*)d_in[20];
    float* out = (float*)d_out;

    const int S = in_sizes[0] / KDIM;
    const int E = in_sizes[1] / KDIM;
    const int B = in_sizes[19];
    const int n1 = in_sizes[11], n0 = in_sizes[13];
    const int m1 = in_sizes[15], m0 = in_sizes[17];
    const int ntot = n1 + n0 + m1 + m0;
    const int n_rows = S + E;
    const int NB = (n_rows + 255) / 256;            // 274
    const int nscat = (ntot + SCHUNK - 1) / SCHUNK;
    const int nCnt  = (ntot + CCHUNK - 1) / CCHUNK;

    const int nPrep = (256 * 64 + 128 * 256 + 128 + 255) / 256;   // 193
    const int nEmb  = (n_rows + 63) / 64;                          // 1094

    char* p = (char*)d_ws;
    unsigned short* tab0 = (unsigned short*)p; p += (size_t)n_rows * KDIM * 2;   // 8.96 MB
    unsigned* edges      = (unsigned*)p;       p += (size_t)ntot * 4;            // 16 MB (final)
    unsigned* recPacked  = (unsigned*)p;                                         // 16 MB (temp)
    // tabF aliases recPacked[0..]; tab8 aliases recPacked after tabF's extent.
    unsigned short* tabF = (unsigned short*)recPacked;
    unsigned char* tab8  = (unsigned char*)recPacked + (size_t)n_rows * KDIM * 2;
    p += (size_t)ntot * 4;
    unsigned char* recRow = (unsigned char*)p; p += (size_t)ntot;                // 4 MB (temp)
    int* ptr    = (int*)p;                     p += (size_t)(n_rows + 1) * 4;
    int* bktCnt = (int*)p;                     p += (size_t)NBPAD * 4;
    int* bktBase= (int*)p;                     p += (size_t)(NBPAD + 1) * 4;
    int* gcurA  = (int*)p;                     p += (size_t)NBPAD * 4;
    p = (char*)(((uintptr_t)p + 255) & ~(uintptr_t)255);     // 16B+ align for vec loads
    unsigned short* W1t = (unsigned short*)p;  p += 256 * 64 * 2;                // 32 KB
    unsigned short* W2t = (unsigned short*)p;  p += 128 * 256 * 2;               // 64 KB
    float* w3r          = (float*)p;           p += 128 * 4;
    p = (char*)(((uintptr_t)p + 255) & ~(uintptr_t)255);
    int* hseg           = (int*)p;             p += (size_t)NB * YSPLIT * 256 * 4; // 2.24 MB

    hipMemsetAsync(bktCnt, 0, (size_t)NBPAD * 4, stream);

    front_fused<<<nPrep + nEmb + nCnt, 256, 0, stream>>>(
        stuW, exerW, knowW, W1, W2, W3,
        ui1_idx, ui0_idx, iu1_idx, iu0_idx,
        n1, n0, m1, S, n_rows, ntot, NB,
        tab0, W1t, W2t, w3r,
        bktCnt, nPrep, nEmb);

    scan_tiny<<<1, 256, 0, stream>>>(bktCnt, bktBase, gcurA, NB);

    bin_scatter<<<nscat, 256, 0, stream>>>(
        ui1_idx, ui1_val, ui0_idx, ui0_val, iu1_idx, iu1_val, iu0_idx, iu0_val,
        n1, n0, m1, m0, S, gcurA, recPacked, recRow, ntot, NB);

    row_hist<<<dim3(NB, YSPLIT), 256, 0, stream>>>(recRow, bktBase, hseg);

    row_sort2<<<dim3(NB, YSPLIT), 256, 0, stream>>>(recPacked, recRow, bktBase, hseg,
                                                    ptr, edges, n_rows, NB);

    // tab8 lives in recPacked's region (dead after row_sort2, past tabF extent)
    to_fp8<<<(n_rows * KDIM / 16 + 255) / 256, 256, 0, stream>>>(tab0, tab8, n_rows * KDIM);

    pull_spmm<<<(n_rows + 3) / 4, 256, 0, stream>>>(tab0, tab8, ptr, edges,
                                                    tabF, S, n_rows);

    tail_mlp<<<(B + 63) / 64, 256, 0, stream>>>(tabF, discW,
                                                W1t, b1, W2t, b2, w3r, b3,
                                                kn, stu_id, exer_id, out, S, B);
}

// Round 19
// 182.602 us; speedup vs baseline: 1.3373x; 1.3373x over previous
//
#include <hip/hip_runtime.h>

#define KDIM 64
#define NBPAD 512          // padded bucket-array size (NB = 274 here)
#define CHUNK 4096         // records per bin_scatter / count block
#define YSPLIT 8           // row sort segments per bucket

typedef __attribute__((ext_vector_type(8))) short short8v;   // 8 bf16 (4 VGPRs)
typedef __attribute__((ext_vector_type(4))) float f32x4;     // MFMA acc
typedef __attribute__((ext_vector_type(2))) float f32x2;     // fp8 cvt result

__device__ __forceinline__ float bf16u_to_f(unsigned short u) {
    return __uint_as_float(((unsigned)u) << 16);
}
__device__ __forceinline__ float bf16lo(unsigned u) {
    return __uint_as_float(u << 16);
}
__device__ __forceinline__ float bf16hi(unsigned u) {
    return __uint_as_float(u & 0xFFFF0000u);
}
__device__ __forceinline__ unsigned short f_to_bf16u(float f) {
    unsigned b = __float_as_uint(f);
    b += 0x7FFF + ((b >> 16) & 1);          // round-to-nearest-even
    return (unsigned short)(b >> 16);
}
__device__ __forceinline__ unsigned pack2bf16(float lo, float hi) {
    return ((unsigned)f_to_bf16u(lo)) | (((unsigned)f_to_bf16u(hi)) << 16);
}
__device__ __forceinline__ float sigmoidf_(float x) {
    return 1.f / (1.f + __expf(-x));
}

// Unified row space over the 4 concatenated edge lists:
// [0,S) students (ui1,ui0), [S,S+E) exercises (iu1,iu0).
__device__ __forceinline__ int dec_row(int e,
    const int* __restrict__ i1, const int* __restrict__ i0,
    const int* __restrict__ j1, const int* __restrict__ j0,
    int n1, int n0, int m1, int S_)
{
    if (e < n1) return i1[e];
    e -= n1;
    if (e < n0) return i0[e];
    e -= n0;
    if (e < m1) return S_ + j1[e];
    e -= m1;
    return S_ + j0[e];
}

__device__ __forceinline__ void dec_full(int e,
    const int* __restrict__ i1, const float* __restrict__ v1,
    const int* __restrict__ i0, const float* __restrict__ v0,
    const int* __restrict__ j1, const float* __restrict__ w1,
    const int* __restrict__ j0, const float* __restrict__ w0,
    int n1, int n0, int m1, int m0, int S_,
    unsigned& row, unsigned& pk)
{
    int col; float v;
    if (e < n1) { row = (unsigned)i1[e]; col = i1[n1 + e]; v = v1[e]; }
    else if (e < n1 + n0) { int le = e - n1; row = (unsigned)i0[le]; col = i0[n0 + le]; v = v0[le]; }
    else if (e < n1 + n0 + m1) { int le = e - n1 - n0; row = (unsigned)(S_ + j1[le]); col = j1[m1 + le]; v = w1[le]; }
    else { int le = e - n1 - n0 - m1; row = (unsigned)(S_ + j0[le]); col = j0[m0 + le]; v = w0[le]; }
    pk = ((unsigned)col << 16) | (unsigned)f_to_bf16u(v);
}

// -------- front_fused: [prep weights | embed MFMA | per-chunk bucket hist]
// Three independent roles by blockIdx range; NO global atomics anywhere.
// Role 3 stores its chunk's 274 bucket counts to hcb[b][bx] (plain stores).
__global__ __launch_bounds__(256) void front_fused(
    const float* __restrict__ stuW, const float* __restrict__ exerW,
    const float* __restrict__ knowW,
    const float* __restrict__ W1, const float* __restrict__ W2,
    const float* __restrict__ W3,
    const int* __restrict__ i1, const int* __restrict__ i0,
    const int* __restrict__ j1, const int* __restrict__ j0,
    int n1, int n0, int m1, int S_, int n_rows, int ntot, int NB,
    unsigned short* __restrict__ tab0,
    unsigned short* __restrict__ W1t, unsigned short* __restrict__ W2t,
    float* __restrict__ w3r,
    int* __restrict__ hcb, int nCnt,
    int nPrep, int nEmb)
{
    __shared__ int shmem[NBPAD];
    const int tid = threadIdx.x;
    int bx = blockIdx.x;

    // ---------------- role 1: weight prep (W1t/W2t/w3r) ----------------
    if (bx < nPrep) {
        int i = bx * 256 + tid;
        if (i < 256 * 64) {                     // W1t[n][k] = relu(W1[k][n])
            int n = i >> 6, k = i & 63;
            W1t[i] = f_to_bf16u(fmaxf(W1[k * 256 + n], 0.f));
            return;
        }
        int j = i - 256 * 64;
        if (j < 128 * 256) {                    // W2t[n][k] = relu(W2[k][n])
            int n = j >> 8, k = j & 255;
            W2t[j] = f_to_bf16u(fmaxf(W2[k * 128 + n], 0.f));
            return;
        }
        int l = j - 128 * 256;
        if (l < 128) w3r[l] = fmaxf(W3[l], 0.f);
        return;
    }
    bx -= nPrep;

    // ---------------- role 2: embed MFMA (64 rows/block) ----------------
    if (bx < nEmb) {
        const int w = tid >> 6, l = tid & 63;
        const int lr = l & 15, lg = l >> 4;
        const int r0 = bx * 64 + 16 * w;

        const int arow = min(r0 + lr, n_rows - 1);
        const float* a = (arow < S_) ? (stuW + (size_t)arow * KDIM)
                                     : (exerW + (size_t)(arow - S_) * KDIM);
        float4 v0 = *((const float4*)(a + lg * 8));
        float4 v1 = *((const float4*)(a + lg * 8 + 4));
        float4 v2 = *((const float4*)(a + 32 + lg * 8));
        float4 v3 = *((const float4*)(a + 32 + lg * 8 + 4));
        union { unsigned u[4]; short8v s; } A0, A1;
        A0.u[0] = pack2bf16(v0.x, v0.y); A0.u[1] = pack2bf16(v0.z, v0.w);
        A0.u[2] = pack2bf16(v1.x, v1.y); A0.u[3] = pack2bf16(v1.z, v1.w);
        A1.u[0] = pack2bf16(v2.x, v2.y); A1.u[1] = pack2bf16(v2.z, v2.w);
        A1.u[2] = pack2bf16(v3.x, v3.y); A1.u[3] = pack2bf16(v3.z, v3.w);

        #pragma unroll
        for (int n = 0; n < 4; ++n) {
            const float* kb = knowW + (size_t)(n * 16 + lr) * KDIM + lg * 8;
            float4 b0f = *(const float4*)kb;
            float4 b0g = *(const float4*)(kb + 4);
            float4 b1f = *(const float4*)(kb + 32);
            float4 b1g = *(const float4*)(kb + 36);
            union { unsigned u[4]; short8v s; } B0, B1;
            B0.u[0] = pack2bf16(b0f.x, b0f.y); B0.u[1] = pack2bf16(b0f.z, b0f.w);
            B0.u[2] = pack2bf16(b0g.x, b0g.y); B0.u[3] = pack2bf16(b0g.z, b0g.w);
            B1.u[0] = pack2bf16(b1f.x, b1f.y); B1.u[1] = pack2bf16(b1f.z, b1f.w);
            B1.u[2] = pack2bf16(b1g.x, b1g.y); B1.u[3] = pack2bf16(b1g.z, b1g.w);
            f32x4 acc = {0.f, 0.f, 0.f, 0.f};
            acc = __builtin_amdgcn_mfma_f32_16x16x32_bf16(A0.s, B0.s, acc, 0, 0, 0);
            acc = __builtin_amdgcn_mfma_f32_16x16x32_bf16(A1.s, B1.s, acc, 0, 0, 0);
            #pragma unroll
            for (int q = 0; q < 4; ++q) {
                int srow = r0 + lg * 4 + q;
                if (srow < n_rows)
                    tab0[(size_t)srow * KDIM + n * 16 + lr] = f_to_bf16u(sigmoidf_(acc[q]));
            }
        }
        return;
    }
    bx -= nEmb;

    // ---------------- role 3: per-chunk bucket histogram ----------------
    for (int i = tid; i < NBPAD; i += 256) shmem[i] = 0;
    __syncthreads();
    const int e0 = bx * CHUNK;
    #pragma unroll
    for (int it = 0; it < 16; ++it) {
        int e = e0 + it * 256 + tid;
        if (e < ntot) atomicAdd(&shmem[dec_row(e, i1, i0, j1, j0, n1, n0, m1, S_) >> 8], 1);
    }
    __syncthreads();
    for (int b = tid; b < NB; b += 256)
        hcb[(size_t)b * nCnt + bx] = shmem[b];     // plain store, no atomics
}

// -------- col_scan: per bucket b, exclusive prefix over chunks (in place);
// total -> bktCnt[b]. Contiguous row reads; 274 blocks.
__global__ __launch_bounds__(256) void col_scan(
    int* __restrict__ hcb, int* __restrict__ bktCnt, int nCnt)
{
    __shared__ int sc[256];
    const int b = blockIdx.x, tid = threadIdx.x;
    int* row = hcb + (size_t)b * nCnt;
    int carry = 0;
    for (int t0 = 0; t0 < nCnt; t0 += 256) {
        int idx = t0 + tid;
        int v = (idx < nCnt) ? row[idx] : 0;
        sc[tid] = v;
        __syncthreads();
        for (int o = 1; o < 256; o <<= 1) {
            int a = (tid >= o) ? sc[tid - o] : 0;
            __syncthreads();
            sc[tid] += a;
            __syncthreads();
        }
        if (idx < nCnt) row[idx] = carry + sc[tid] - v;   // exclusive
        carry += sc[255];
        __syncthreads();
    }
    if (tid == 0) bktCnt[b] = carry;
}

// -------- exclusive scan of NB bucket counts -> bktBase
__global__ __launch_bounds__(256) void scan_tiny(
    const int* __restrict__ bktCnt, int* __restrict__ bktBase, int NB)
{
    __shared__ int s[NBPAD + 1];
    for (int i = threadIdx.x; i < NB; i += 256) s[i] = bktCnt[i];
    __syncthreads();
    if (threadIdx.x == 0) {
        int acc = 0;
        for (int b = 0; b < NB; ++b) { int c = s[b]; s[b] = acc; acc += c; }
        s[NB] = acc;
    }
    __syncthreads();
    for (int i = threadIdx.x; i <= NB; i += 256) bktBase[i] = s[i];
}

// -------- binned scatter v5: NO global atomics — gdst comes from the
// precomputed deterministic chunk offsets (bktBase[b] + hcb[b][bx]).
// Single LDS atomic per record (hist return value = slot), shfl 512-prefix.
__global__ __launch_bounds__(256) void bin_scatter(
    const int* __restrict__ i1, const float* __restrict__ v1,
    const int* __restrict__ i0, const float* __restrict__ v0,
    const int* __restrict__ j1, const float* __restrict__ w1,
    const int* __restrict__ j0, const float* __restrict__ w0,
    int n1, int n0, int m1, int m0, int S_,
    const int* __restrict__ bktBase, const int* __restrict__ hcb, int nCnt,
    unsigned* __restrict__ recPacked, unsigned char* __restrict__ recRow,
    int ntot, int NB)
{
    __shared__ int h[NBPAD], sstart[NBPAD], gdst[NBPAD];
    __shared__ int wsum[8];
    __shared__ unsigned stageP[CHUNK];
    __shared__ unsigned stageG[CHUNK];       // (bkt<<8)|rowLocal
    const int tid = threadIdx.x;
    const int bx = blockIdx.x;
    const int e0 = bx * CHUNK;

    for (int i = tid; i < NBPAD; i += 256) h[i] = 0;
    // deterministic global destinations (no atomics) — issue loads early
    if (tid < NB) gdst[tid] = bktBase[tid] + hcb[(size_t)tid * nCnt + bx];
    if (tid + 256 < NB) gdst[tid + 256] = bktBase[tid + 256] + hcb[(size_t)(tid + 256) * nCnt + bx];
    __syncthreads();

    unsigned rrow[16], rpk[16];
    unsigned short rslot[16];
    #pragma unroll
    for (int it = 0; it < 16; ++it) {
        int e = e0 + it * 256 + tid;
        if (e < ntot) {
            dec_full(e, i1, v1, i0, v0, j1, w1, j0, w0, n1, n0, m1, m0, S_,
                     rrow[it], rpk[it]);
            rslot[it] = (unsigned short)atomicAdd(&h[rrow[it] >> 8], 1);
        } else {
            rrow[it] = 0xFFFFFFFFu;
        }
    }
    __syncthreads();

    {   // exclusive prefix over 512 buckets: per-wave shfl scans, one exchange.
        const int wv = tid >> 6, ln = tid & 63;
        int v0h = h[tid];
        int v1h = h[tid + 256];
        int s0 = v0h, s1 = v1h;
        #pragma unroll
        for (int o = 1; o < 64; o <<= 1) {
            int t0 = __shfl_up(s0, o);
            int t1 = __shfl_up(s1, o);
            if (ln >= o) { s0 += t0; s1 += t1; }
        }
        if (ln == 63) { wsum[wv] = s0; wsum[4 + wv] = s1; }
        __syncthreads();
        int woff0 = 0, total0 = 0, woff1lo = 0;
        #pragma unroll
        for (int i = 0; i < 4; ++i) {
            int wl = wsum[i], wh = wsum[4 + i];
            total0 += wl;
            if (i < wv) { woff0 += wl; woff1lo += wh; }
        }
        sstart[tid] = woff0 + s0 - v0h;
        sstart[tid + 256] = total0 + woff1lo + s1 - v1h;
    }
    __syncthreads();

    #pragma unroll
    for (int it = 0; it < 16; ++it) {
        if (rrow[it] != 0xFFFFFFFFu) {
            int slot = sstart[rrow[it] >> 8] + (int)rslot[it];   // no atomics
            stageP[slot] = rpk[it];
            stageG[slot] = rrow[it];
        }
    }
    __syncthreads();

    int cnt = ntot - e0; if (cnt > CHUNK) cnt = CHUNK;
    for (int i = tid; i < cnt; i += 256) {
        unsigned gr = stageG[i];
        int bkt = gr >> 8;
        int dst = gdst[bkt] + (i - sstart[bkt]);
        recPacked[dst] = stageP[i];
        recRow[dst]   = (unsigned char)(gr & 255u);
    }
}

// -------- row_hist: block (b,y) histograms ONLY its segment -> hseg[b][y][256].
__global__ __launch_bounds__(256) void row_hist(
    const unsigned char* __restrict__ recRow, const int* __restrict__ bktBase,
    int* __restrict__ hseg)
{
    __shared__ int h[256];
    const int b = blockIdx.x, y = blockIdx.y, tid = threadIdx.x;
    const int start = bktBase[b], end = bktBase[b + 1];
    const int seg = (end - start + YSPLIT - 1) / YSPLIT;
    int myS = start + y * seg;  if (myS > end) myS = end;
    int myE = myS + seg;        if (myE > end) myE = end;

    h[tid] = 0;
    __syncthreads();
    for (int i = myS + tid; i < myE; i += 256)
        atomicAdd(&h[(int)recRow[i]], 1);
    __syncthreads();
    hseg[((size_t)b * YSPLIT + y) * 256 + tid] = h[tid];
}

// -------- row_sort2: merge segment histograms, scan, scatter own segment.
__global__ __launch_bounds__(256) void row_sort2(
    const unsigned* __restrict__ recPacked, const unsigned char* __restrict__ recRow,
    const int* __restrict__ bktBase, const int* __restrict__ hseg,
    int* __restrict__ ptr, unsigned* __restrict__ edges, int n_rows, int NB)
{
    __shared__ int sc[256], cur[256];
    const int b = blockIdx.x, y = blockIdx.y, tid = threadIdx.x;
    const int r0 = b << 8;
    const int start = bktBase[b], end = bktBase[b + 1];
    const int seg = (end - start + YSPLIT - 1) / YSPLIT;
    int myS = start + y * seg;  if (myS > end) myS = end;
    int myE = myS + seg;        if (myE > end) myE = end;

    int ht = 0, hb = 0;
    const int* hsb = hseg + (size_t)b * YSPLIT * 256 + tid;
    #pragma unroll
    for (int yy = 0; yy < YSPLIT; ++yy) {
        int v = hsb[yy * 256];
        ht += v;
        hb += (yy < y) ? v : 0;
    }

    sc[tid] = ht;
    __syncthreads();
    for (int o = 1; o < 256; o <<= 1) {
        int add = (tid >= o) ? sc[tid - o] : 0;
        __syncthreads();
        sc[tid] += add;
        __syncthreads();
    }
    const int excl = sc[tid] - ht;

    if (y == 0) {
        int grow = r0 + tid;
        if (grow < n_rows) ptr[grow] = start + excl;
        if (b == NB - 1 && tid == 0) ptr[n_rows] = end;
    }
    cur[tid] = excl + hb;
    __syncthreads();

    for (int i = myS + tid; i < myE; i += 256) {
        unsigned pk = recPacked[i];
        int r = (int)recRow[i];
        int dst = start + atomicAdd(&cur[r], 1);
        edges[dst] = pk;
    }
}

// -------- to_fp8: tab0 (bf16) -> tab8 (fp8 e4m3), 16 elems/thread (vectorized).
__global__ __launch_bounds__(256) void to_fp8(
    const unsigned short* __restrict__ tab0, unsigned char* __restrict__ tab8, int n)
{
    int i = blockIdx.x * 256 + threadIdx.x;
    if (i * 16 >= n) return;
    uint4 a = ((const uint4*)tab0)[i * 2];
    uint4 b = ((const uint4*)tab0)[i * 2 + 1];
    uint4 o;
    int t;
    t = __builtin_amdgcn_cvt_pk_fp8_f32(bf16lo(a.x), bf16hi(a.x), 0, false);
    o.x = (unsigned)__builtin_amdgcn_cvt_pk_fp8_f32(bf16lo(a.y), bf16hi(a.y), t, true);
    t = __builtin_amdgcn_cvt_pk_fp8_f32(bf16lo(a.z), bf16hi(a.z), 0, false);
    o.y = (unsigned)__builtin_amdgcn_cvt_pk_fp8_f32(bf16lo(a.w), bf16hi(a.w), t, true);
    t = __builtin_amdgcn_cvt_pk_fp8_f32(bf16lo(b.x), bf16hi(b.x), 0, false);
    o.z = (unsigned)__builtin_amdgcn_cvt_pk_fp8_f32(bf16lo(b.y), bf16hi(b.y), t, true);
    t = __builtin_amdgcn_cvt_pk_fp8_f32(bf16lo(b.z), bf16hi(b.z), 0, false);
    o.w = (unsigned)__builtin_amdgcn_cvt_pk_fp8_f32(bf16lo(b.w), bf16hi(b.w), t, true);
    ((uint4*)tab8)[i] = o;
}

// -------- Pull SpMM v4: fp8 gather + packed f32x2 accumulation.
__global__ __launch_bounds__(256) void pull_spmm(
    const unsigned short* __restrict__ tab0,
    const unsigned char* __restrict__ tab8,
    const int* __restrict__ ptr, const unsigned* __restrict__ edges,
    unsigned short* __restrict__ tabF, int S_, int n_rows)
{
    const int w = blockIdx.x * 4 + (threadIdx.x >> 6);
    if (w >= n_rows) return;
    const int lane = threadIdx.x & 63;
    const int g = lane >> 3;      // 8 edge-groups
    const int s = lane & 7;       // k-range 8s..8s+7

    const unsigned char* X8 = tab8 + ((w < S_) ? ((size_t)S_ << 6) : (size_t)0)
                                   + (size_t)s * 8;

    f32x2 acc2[4];
    #pragma unroll
    for (int i = 0; i < 4; ++i) acc2[i] = (f32x2){0.f, 0.f};

    int e = ptr[w];
    const int ee = ptr[w + 1];
    unsigned u = (e + lane < ee) ? edges[e + lane] : 0u;
    while (e < ee) {
        int m = ee - e; if (m > 64) m = 64;
        unsigned un = (e + 64 + lane < ee) ? edges[e + 64 + lane] : 0u;  // prefetch
        int iters = (m + 7) >> 3;
        #pragma unroll 4
        for (int jj = 0; jj < iters; ++jj) {
            unsigned uj = __shfl(u, jj * 8 + g);     // 0-word: col 0, val 0 -> harmless
            float v = __uint_as_float(uj << 16);     // low 16 = bf16 val
            f32x2 vv = {v, v};
            uint2 xv = *(const uint2*)(X8 + (((size_t)(uj >> 16)) << 6));
            acc2[0] = __builtin_amdgcn_cvt_pk_f32_fp8(xv.x, false) * vv + acc2[0];
            acc2[1] = __builtin_amdgcn_cvt_pk_f32_fp8(xv.x, true)  * vv + acc2[1];
            acc2[2] = __builtin_amdgcn_cvt_pk_f32_fp8(xv.y, false) * vv + acc2[2];
            acc2[3] = __builtin_amdgcn_cvt_pk_f32_fp8(xv.y, true)  * vv + acc2[3];
        }
        u = un;
        e += m;
    }

    #pragma unroll
    for (int i = 0; i < 4; ++i) {
        #pragma unroll
        for (int c = 0; c < 2; ++c) {
            acc2[i][c] += __shfl_xor(acc2[i][c], 8);
            acc2[i][c] += __shfl_xor(acc2[i][c], 16);
            acc2[i][c] += __shfl_xor(acc2[i][c], 32);
        }
    }

    if (g == 0) {
        const uint4 x0 = *(const uint4*)(tab0 + ((size_t)w << 6) + (size_t)s * 8);
        uint4 o;
        o.x = pack2bf16(acc2[0][0] + bf16lo(x0.x), acc2[0][1] + bf16hi(x0.x));
        o.y = pack2bf16(acc2[1][0] + bf16lo(x0.y), acc2[1][1] + bf16hi(x0.y));
        o.z = pack2bf16(acc2[2][0] + bf16lo(x0.z), acc2[2][1] + bf16hi(x0.z));
        o.w = pack2bf16(acc2[3][0] + bf16lo(x0.w), acc2[3][1] + bf16hi(x0.w));
        *(uint4*)(tabF + ((size_t)w << 6) + (size_t)s * 8) = o;
    }
}

// -------- MFMA tail: gather -> GEMM1(64x256x64) -> GEMM2(64x128x256) -> dot.
__global__ __launch_bounds__(256, 1) void tail_mlp(
    const unsigned short* __restrict__ tabF,
    const float* __restrict__ discW,
    const unsigned short* __restrict__ W1t, const float* __restrict__ b1,
    const unsigned short* __restrict__ W2t, const float* __restrict__ b2,
    const float* __restrict__ w3r, const float* __restrict__ b3,
    const float* __restrict__ kn, const int* __restrict__ stu_id,
    const int* __restrict__ exer_id, float* __restrict__ out, int S_, int B)
{
    __shared__ __align__(16) unsigned short xs_bf[64][72];   // 9.0 KB (pad: 2-way banks)
    __shared__ __align__(16) unsigned short h1s[64][264];    // 33.0 KB
    __shared__ __align__(16) unsigned short h2s[64][136];    // 17.0 KB
    __shared__ float b1s[256], b2s[128], w3s[128];
    const int tid = threadIdx.x;
    const int b0 = blockIdx.x * 64;

    b1s[tid] = b1[tid];
    if (tid < 128) { b2s[tid] = b2[tid]; w3s[tid] = w3r[tid]; }

    // ---- phase 0: x = disc*(stat-diff)/3*kn -> bf16 LDS tile (vectorized x4)
    #pragma unroll
    for (int i = 0; i < 4; ++i) {
        int e4 = (i * 256 + tid) * 4;
        int r = e4 >> 6, k0 = e4 & 63;
        int b = b0 + r;
        float4 x4 = make_float4(0.f, 0.f, 0.f, 0.f);
        if (b < B) {
            int sid = stu_id[b], eid = exer_id[b];
            float c = sigmoidf_(discW[eid]) * (1.f / 3.f);
            ushort4 st4 = *((const ushort4*)(tabF + (size_t)sid * 64 + k0));
            ushort4 df4 = *((const ushort4*)(tabF + ((size_t)(S_ + eid)) * 64 + k0));
            float4 kn4 = *((const float4*)(kn + (size_t)b * 64 + k0));
            x4.x = c * (bf16u_to_f(st4.x) - bf16u_to_f(df4.x)) * kn4.x;
            x4.y = c * (bf16u_to_f(st4.y) - bf16u_to_f(df4.y)) * kn4.y;
            x4.z = c * (bf16u_to_f(st4.z) - bf16u_to_f(df4.z)) * kn4.z;
            x4.w = c * (bf16u_to_f(st4.w) - bf16u_to_f(df4.w)) * kn4.w;
        }
        ushort4 xb;
        xb.x = f_to_bf16u(x4.x); xb.y = f_to_bf16u(x4.y);
        xb.z = f_to_bf16u(x4.z); xb.w = f_to_bf16u(x4.w);
        *((ushort4*)&xs_bf[r][k0]) = xb;
    }
    __syncthreads();

    const int w  = tid >> 6;
    const int l  = tid & 63;
    const int lr = l & 15;        // A row / B col / C col
    const int lg = l >> 4;        // k-group (8 contig k each)

    // ---- GEMM1: H1 = sigmoid(X[64x64] @ W1r[64x256] + b1)
    {
        short8v a0 = *(const short8v*)&xs_bf[16 * w + lr][lg * 8];
        short8v a1 = *(const short8v*)&xs_bf[16 * w + lr][32 + lg * 8];
        const unsigned short* w1base = W1t + (size_t)lr * 64 + lg * 8;
        #pragma unroll 4
        for (int n = 0; n < 16; ++n) {
            short8v bb0 = *(const short8v*)(w1base + n * 1024);
            short8v bb1 = *(const short8v*)(w1base + n * 1024 + 32);
            f32x4 acc = {0.f, 0.f, 0.f, 0.f};
            acc = __builtin_amdgcn_mfma_f32_16x16x32_bf16(a0, bb0, acc, 0, 0, 0);
            acc = __builtin_amdgcn_mfma_f32_16x16x32_bf16(a1, bb1, acc, 0, 0, 0);
            int col = n * 16 + lr;
            float bias = b1s[col];
            #pragma unroll
            for (int q = 0; q < 4; ++q)
                h1s[16 * w + lg * 4 + q][col] = f_to_bf16u(sigmoidf_(acc[q] + bias));
        }
    }
    __syncthreads();

    // ---- GEMM2: H2 = sigmoid(H1[64x256] @ W2r[256x128] + b2)
    {
        short8v ak[8];
        #pragma unroll
        for (int kk = 0; kk < 8; ++kk)
            ak[kk] = *(const short8v*)&h1s[16 * w + lr][kk * 32 + lg * 8];
        const unsigned short* w2base = W2t + (size_t)lr * 256 + lg * 8;
        #pragma unroll 2
        for (int n = 0; n < 8; ++n) {
            const unsigned short* bp = w2base + (size_t)n * 16 * 256;
            f32x4 acc = {0.f, 0.f, 0.f, 0.f};
            #pragma unroll
            for (int kk = 0; kk < 8; ++kk) {
                short8v bb = *(const short8v*)(bp + kk * 32);
                acc = __builtin_amdgcn_mfma_f32_16x16x32_bf16(ak[kk], bb, acc, 0, 0, 0);
            }
            int col = n * 16 + lr;
            float bias = b2s[col];
            #pragma unroll
            for (int q = 0; q < 4; ++q)
                h2s[16 * w + lg * 4 + q][col] = f_to_bf16u(sigmoidf_(acc[q] + bias));
        }
    }
    __syncthreads();

    // ---- GEMM3: out = sigmoid(H2 @ w3r + b3)   (64 rows, VALU)
    if (tid < 64) {
        int b = b0 + tid;
        if (b < B) {
            float acc = b3[0];
            const unsigned* h2r = (const unsigned*)&h2s[tid][0];
            #pragma unroll 8
            for (int jj = 0; jj < 64; ++jj) {
                unsigned hv = h2r[jj];
                acc += bf16lo(hv) * w3s[jj * 2 + 0] + bf16hi(hv) * w3s[jj * 2 + 1];
            }
            out[b] = sigmoidf_(acc);
        }
    }
}

extern "C" void kernel_launch(void* const* d_in, const int* in_sizes, int n_in,
                              void* d_out, int out_size, void* d_ws, size_t ws_size,
                              hipStream_t stream) {
    const float* stuW  = (const float*)d_in[0];
    const float* exerW = (const float*)d_in[1];
    const float* knowW = (const float*)d_in[2];
    const float* discW = (const float*)d_in[3];
    const float* W1 = (const float*)d_in[4];
    const float* b1 = (const float*)d_in[5];
    const float* W2 = (const float*)d_in[6];
    const float* b2 = (const float*)d_in[7];
    const float* W3 = (const float*)d_in[8];
    const float* b3 = (const float*)d_in[9];
    const int*   ui1_idx = (const int*)d_in[10];
    const float* ui1_val = (const float*)d_in[11];
    const int*   ui0_idx = (const int*)d_in[12];
    const float* ui0_val = (const float*)d_in[13];
    const int*   iu1_idx = (const int*)d_in[14];
    const float* iu1_val = (const float*)d_in[15];
    const int*   iu0_idx = (const int*)d_in[16];
    const float* iu0_val = (const float*)d_in[17];
    const float* kn      = (const float*)d_in[18];
    const int*   stu_id  = (const int*)d_in[19];
    const int*   exer_id = (const int*)d_in[20];
    float* out = (float*)d_out;

    const int S = in_sizes[0] / KDIM;
    const int E = in_sizes[1] / KDIM;
    const int B = in_sizes[19];
    const int n1 = in_sizes[11], n0 = in_sizes[13];
    const int m1 = in_sizes[15], m0 = in_sizes[17];
    const int ntot = n1 + n0 + m1 + m0;
    const int n_rows = S + E;
    const int NB = (n_rows + 255) / 256;            // 274
    const int nCnt = (ntot + CHUNK - 1) / CHUNK;    // 977

    const int nPrep = (256 * 64 + 128 * 256 + 128 + 255) / 256;   // 193
    const int nEmb  = (n_rows + 63) / 64;                          // 1094

    char* p = (char*)d_ws;
    unsigned short* tab0 = (unsigned short*)p; p += (size_t)n_rows * KDIM * 2;   // 8.96 MB
    unsigned* edges      = (unsigned*)p;       p += (size_t)ntot * 4;            // 16 MB (final)
    unsigned* recPacked  = (unsigned*)p;                                         // 16 MB (temp)
    // tabF aliases recPacked[0..]; tab8 aliases recPacked after tabF's extent.
    unsigned short* tabF = (unsigned short*)recPacked;
    unsigned char* tab8  = (unsigned char*)recPacked + (size_t)n_rows * KDIM * 2;
    p += (size_t)ntot * 4;
    unsigned char* recRow = (unsigned char*)p; p += (size_t)ntot;                // 4 MB (temp)
    int* ptr    = (int*)p;                     p += (size_t)(n_rows + 1) * 4;
    int* bktCnt = (int*)p;                     p += (size_t)NBPAD * 4;
    int* bktBase= (int*)p;                     p += (size_t)(NBPAD + 1) * 4;
    p = (char*)(((uintptr_t)p + 255) & ~(uintptr_t)255);     // 16B+ align for vec loads
    unsigned short* W1t = (unsigned short*)p;  p += 256 * 64 * 2;                // 32 KB
    unsigned short* W2t = (unsigned short*)p;  p += 128 * 256 * 2;               // 64 KB
    float* w3r          = (float*)p;           p += 128 * 4;
    p = (char*)(((uintptr_t)p + 255) & ~(uintptr_t)255);
    int* hseg           = (int*)p;             p += (size_t)NB * YSPLIT * 256 * 4; // 2.24 MB
    p = (char*)(((uintptr_t)p + 255) & ~(uintptr_t)255);
    int* hcb            = (int*)p;             p += (size_t)NB * nCnt * 4;         // 1.07 MB

    front_fused<<<nPrep + nEmb + nCnt, 256, 0, stream>>>(
        stuW, exerW, knowW, W1, W2, W3,
        ui1_idx, ui0_idx, iu1_idx, iu0_idx,
        n1, n0, m1, S, n_rows, ntot, NB,
        tab0, W1t, W2t, w3r,
        hcb, nCnt, nPrep, nEmb);

    col_scan<<<NB, 256, 0, stream>>>(hcb, bktCnt, nCnt);

    scan_tiny<<<1, 256, 0, stream>>>(bktCnt, bktBase, NB);

    bin_scatter<<<nCnt, 256, 0, stream>>>(
        ui1_idx, ui1_val, ui0_idx, ui0_val, iu1_idx, iu1_val, iu0_idx, iu0_val,
        n1, n0, m1, m0, S, bktBase, hcb, nCnt, recPacked, recRow, ntot, NB);

    row_hist<<<dim3(NB, YSPLIT), 256, 0, stream>>>(recRow, bktBase, hseg);

    row_sort2<<<dim3(NB, YSPLIT), 256, 0, stream>>>(recPacked, recRow, bktBase, hseg,
                                                    ptr, edges, n_rows, NB);

    // tab8 lives in recPacked's region (dead after row_sort2, past tabF extent)
    to_fp8<<<(n_rows * KDIM / 16 + 255) / 256, 256, 0, stream>>>(tab0, tab8, n_rows * KDIM);

    pull_spmm<<<(n_rows + 3) / 4, 256, 0, stream>>>(tab0, tab8, ptr, edges,
                                                    tabF, S, n_rows);

    tail_mlp<<<(B + 63) / 64, 256, 0, stream>>>(tabF, discW,
                                                W1t, b1, W2t, b2, w3r, b3,
                                                kn, stu_id, exer_id, out, S, B);
}

// Round 20
// 181.698 us; speedup vs baseline: 1.3439x; 1.0050x over previous
//
#include <hip/hip_runtime.h>

#define KDIM 64
#define NBPAD 512          // padded bucket-array size (NB = 274 here)
#define CHUNK 4096         // records per bin_scatter / count block
#define YSPLIT 8           // row sort segments per bucket

typedef __attribute__((ext_vector_type(8))) short short8v;   // 8 bf16 (4 VGPRs)
typedef __attribute__((ext_vector_type(4))) float f32x4;     // MFMA acc
typedef __attribute__((ext_vector_type(2))) float f32x2;     // fp8 cvt result

__device__ __forceinline__ float bf16u_to_f(unsigned short u) {
    return __uint_as_float(((unsigned)u) << 16);
}
__device__ __forceinline__ float bf16lo(unsigned u) {
    return __uint_as_float(u << 16);
}
__device__ __forceinline__ float bf16hi(unsigned u) {
    return __uint_as_float(u & 0xFFFF0000u);
}
__device__ __forceinline__ unsigned short f_to_bf16u(float f) {
    unsigned b = __float_as_uint(f);
    b += 0x7FFF + ((b >> 16) & 1);          // round-to-nearest-even
    return (unsigned short)(b >> 16);
}
__device__ __forceinline__ unsigned pack2bf16(float lo, float hi) {
    return ((unsigned)f_to_bf16u(lo)) | (((unsigned)f_to_bf16u(hi)) << 16);
}
__device__ __forceinline__ float sigmoidf_(float x) {
    return 1.f / (1.f + __expf(-x));
}

// Unified row space over the 4 concatenated edge lists:
// [0,S) students (ui1,ui0), [S,S+E) exercises (iu1,iu0).
__device__ __forceinline__ int dec_row(int e,
    const int* __restrict__ i1, const int* __restrict__ i0,
    const int* __restrict__ j1, const int* __restrict__ j0,
    int n1, int n0, int m1, int S_)
{
    if (e < n1) return i1[e];
    e -= n1;
    if (e < n0) return i0[e];
    e -= n0;
    if (e < m1) return S_ + j1[e];
    e -= m1;
    return S_ + j0[e];
}

__device__ __forceinline__ void dec_full(int e,
    const int* __restrict__ i1, const float* __restrict__ v1,
    const int* __restrict__ i0, const float* __restrict__ v0,
    const int* __restrict__ j1, const float* __restrict__ w1,
    const int* __restrict__ j0, const float* __restrict__ w0,
    int n1, int n0, int m1, int m0, int S_,
    unsigned& row, unsigned& pk)
{
    int col; float v;
    if (e < n1) { row = (unsigned)i1[e]; col = i1[n1 + e]; v = v1[e]; }
    else if (e < n1 + n0) { int le = e - n1; row = (unsigned)i0[le]; col = i0[n0 + le]; v = v0[le]; }
    else if (e < n1 + n0 + m1) { int le = e - n1 - n0; row = (unsigned)(S_ + j1[le]); col = j1[m1 + le]; v = w1[le]; }
    else { int le = e - n1 - n0 - m1; row = (unsigned)(S_ + j0[le]); col = j0[m0 + le]; v = w0[le]; }
    pk = ((unsigned)col << 16) | (unsigned)f_to_bf16u(v);
}

// -------- front_fused: [prep weights | embed MFMA | per-chunk bucket hist]
// Three independent roles by blockIdx range; NO global atomics anywhere.
__global__ __launch_bounds__(256) void front_fused(
    const float* __restrict__ stuW, const float* __restrict__ exerW,
    const float* __restrict__ knowW,
    const float* __restrict__ W1, const float* __restrict__ W2,
    const float* __restrict__ W3,
    const int* __restrict__ i1, const int* __restrict__ i0,
    const int* __restrict__ j1, const int* __restrict__ j0,
    int n1, int n0, int m1, int S_, int n_rows, int ntot, int NB,
    unsigned short* __restrict__ tab0,
    unsigned short* __restrict__ W1t, unsigned short* __restrict__ W2t,
    float* __restrict__ w3r,
    int* __restrict__ hcb, int nCnt,
    int nPrep, int nEmb)
{
    __shared__ int shmem[NBPAD];
    const int tid = threadIdx.x;
    int bx = blockIdx.x;

    // ---------------- role 1: weight prep (W1t/W2t/w3r) ----------------
    if (bx < nPrep) {
        int i = bx * 256 + tid;
        if (i < 256 * 64) {                     // W1t[n][k] = relu(W1[k][n])
            int n = i >> 6, k = i & 63;
            W1t[i] = f_to_bf16u(fmaxf(W1[k * 256 + n], 0.f));
            return;
        }
        int j = i - 256 * 64;
        if (j < 128 * 256) {                    // W2t[n][k] = relu(W2[k][n])
            int n = j >> 8, k = j & 255;
            W2t[j] = f_to_bf16u(fmaxf(W2[k * 128 + n], 0.f));
            return;
        }
        int l = j - 128 * 256;
        if (l < 128) w3r[l] = fmaxf(W3[l], 0.f);
        return;
    }
    bx -= nPrep;

    // ---------------- role 2: embed MFMA (64 rows/block) ----------------
    if (bx < nEmb) {
        const int w = tid >> 6, l = tid & 63;
        const int lr = l & 15, lg = l >> 4;
        const int r0 = bx * 64 + 16 * w;

        const int arow = min(r0 + lr, n_rows - 1);
        const float* a = (arow < S_) ? (stuW + (size_t)arow * KDIM)
                                     : (exerW + (size_t)(arow - S_) * KDIM);
        float4 v0 = *((const float4*)(a + lg * 8));
        float4 v1 = *((const float4*)(a + lg * 8 + 4));
        float4 v2 = *((const float4*)(a + 32 + lg * 8));
        float4 v3 = *((const float4*)(a + 32 + lg * 8 + 4));
        union { unsigned u[4]; short8v s; } A0, A1;
        A0.u[0] = pack2bf16(v0.x, v0.y); A0.u[1] = pack2bf16(v0.z, v0.w);
        A0.u[2] = pack2bf16(v1.x, v1.y); A0.u[3] = pack2bf16(v1.z, v1.w);
        A1.u[0] = pack2bf16(v2.x, v2.y); A1.u[1] = pack2bf16(v2.z, v2.w);
        A1.u[2] = pack2bf16(v3.x, v3.y); A1.u[3] = pack2bf16(v3.z, v3.w);

        #pragma unroll
        for (int n = 0; n < 4; ++n) {
            const float* kb = knowW + (size_t)(n * 16 + lr) * KDIM + lg * 8;
            float4 b0f = *(const float4*)kb;
            float4 b0g = *(const float4*)(kb + 4);
            float4 b1f = *(const float4*)(kb + 32);
            float4 b1g = *(const float4*)(kb + 36);
            union { unsigned u[4]; short8v s; } B0, B1;
            B0.u[0] = pack2bf16(b0f.x, b0f.y); B0.u[1] = pack2bf16(b0f.z, b0f.w);
            B0.u[2] = pack2bf16(b0g.x, b0g.y); B0.u[3] = pack2bf16(b0g.z, b0g.w);
            B1.u[0] = pack2bf16(b1f.x, b1f.y); B1.u[1] = pack2bf16(b1f.z, b1f.w);
            B1.u[2] = pack2bf16(b1g.x, b1g.y); B1.u[3] = pack2bf16(b1g.z, b1g.w);
            f32x4 acc = {0.f, 0.f, 0.f, 0.f};
            acc = __builtin_amdgcn_mfma_f32_16x16x32_bf16(A0.s, B0.s, acc, 0, 0, 0);
            acc = __builtin_amdgcn_mfma_f32_16x16x32_bf16(A1.s, B1.s, acc, 0, 0, 0);
            #pragma unroll
            for (int q = 0; q < 4; ++q) {
                int srow = r0 + lg * 4 + q;
                if (srow < n_rows)
                    tab0[(size_t)srow * KDIM + n * 16 + lr] = f_to_bf16u(sigmoidf_(acc[q]));
            }
        }
        return;
    }
    bx -= nEmb;

    // ---------------- role 3: per-chunk bucket histogram ----------------
    for (int i = tid; i < NBPAD; i += 256) shmem[i] = 0;
    __syncthreads();
    const int e0 = bx * CHUNK;
    #pragma unroll
    for (int it = 0; it < 16; ++it) {
        int e = e0 + it * 256 + tid;
        if (e < ntot) atomicAdd(&shmem[dec_row(e, i1, i0, j1, j0, n1, n0, m1, S_) >> 8], 1);
    }
    __syncthreads();
    for (int b = tid; b < NB; b += 256)
        hcb[(size_t)b * nCnt + bx] = shmem[b];     // plain store, no atomics
}

// -------- col_scan: per bucket b, exclusive prefix over chunks (in place);
// total -> bktCnt[b]. Contiguous row reads; 274 blocks.
__global__ __launch_bounds__(256) void col_scan(
    int* __restrict__ hcb, int* __restrict__ bktCnt, int nCnt)
{
    __shared__ int sc[256];
    const int b = blockIdx.x, tid = threadIdx.x;
    int* row = hcb + (size_t)b * nCnt;
    int carry = 0;
    for (int t0 = 0; t0 < nCnt; t0 += 256) {
        int idx = t0 + tid;
        int v = (idx < nCnt) ? row[idx] : 0;
        sc[tid] = v;
        __syncthreads();
        for (int o = 1; o < 256; o <<= 1) {
            int a = (tid >= o) ? sc[tid - o] : 0;
            __syncthreads();
            sc[tid] += a;
            __syncthreads();
        }
        if (idx < nCnt) row[idx] = carry + sc[tid] - v;   // exclusive
        carry += sc[255];
        __syncthreads();
    }
    if (tid == 0) bktCnt[b] = carry;
}

// -------- exclusive scan of NB bucket counts -> bktBase
__global__ __launch_bounds__(256) void scan_tiny(
    const int* __restrict__ bktCnt, int* __restrict__ bktBase, int NB)
{
    __shared__ int s[NBPAD + 1];
    for (int i = threadIdx.x; i < NB; i += 256) s[i] = bktCnt[i];
    __syncthreads();
    if (threadIdx.x == 0) {
        int acc = 0;
        for (int b = 0; b < NB; ++b) { int c = s[b]; s[b] = acc; acc += c; }
        s[NB] = acc;
    }
    __syncthreads();
    for (int i = threadIdx.x; i <= NB; i += 256) bktBase[i] = s[i];
}

// -------- binned scatter v5: NO global atomics — gdst from precomputed
// deterministic chunk offsets (bktBase[b] + hcb[b][bx]). Single LDS atomic
// per record (hist return value = slot), shfl 512-prefix.
__global__ __launch_bounds__(256) void bin_scatter(
    const int* __restrict__ i1, const float* __restrict__ v1,
    const int* __restrict__ i0, const float* __restrict__ v0,
    const int* __restrict__ j1, const float* __restrict__ w1,
    const int* __restrict__ j0, const float* __restrict__ w0,
    int n1, int n0, int m1, int m0, int S_,
    const int* __restrict__ bktBase, const int* __restrict__ hcb, int nCnt,
    unsigned* __restrict__ recPacked, unsigned char* __restrict__ recRow,
    int ntot, int NB)
{
    __shared__ int h[NBPAD], sstart[NBPAD], gdst[NBPAD];
    __shared__ int wsum[8];
    __shared__ unsigned stageP[CHUNK];
    __shared__ unsigned stageG[CHUNK];       // (bkt<<8)|rowLocal
    const int tid = threadIdx.x;
    const int bx = blockIdx.x;
    const int e0 = bx * CHUNK;

    for (int i = tid; i < NBPAD; i += 256) h[i] = 0;
    // deterministic global destinations (no atomics) — issue loads early
    if (tid < NB) gdst[tid] = bktBase[tid] + hcb[(size_t)tid * nCnt + bx];
    if (tid + 256 < NB) gdst[tid + 256] = bktBase[tid + 256] + hcb[(size_t)(tid + 256) * nCnt + bx];
    __syncthreads();

    unsigned rrow[16], rpk[16];
    unsigned short rslot[16];
    #pragma unroll
    for (int it = 0; it < 16; ++it) {
        int e = e0 + it * 256 + tid;
        if (e < ntot) {
            dec_full(e, i1, v1, i0, v0, j1, w1, j0, w0, n1, n0, m1, m0, S_,
                     rrow[it], rpk[it]);
            rslot[it] = (unsigned short)atomicAdd(&h[rrow[it] >> 8], 1);
        } else {
            rrow[it] = 0xFFFFFFFFu;
        }
    }
    __syncthreads();

    {   // exclusive prefix over 512 buckets: per-wave shfl scans, one exchange.
        const int wv = tid >> 6, ln = tid & 63;
        int v0h = h[tid];
        int v1h = h[tid + 256];
        int s0 = v0h, s1 = v1h;
        #pragma unroll
        for (int o = 1; o < 64; o <<= 1) {
            int t0 = __shfl_up(s0, o);
            int t1 = __shfl_up(s1, o);
            if (ln >= o) { s0 += t0; s1 += t1; }
        }
        if (ln == 63) { wsum[wv] = s0; wsum[4 + wv] = s1; }
        __syncthreads();
        int woff0 = 0, total0 = 0, woff1lo = 0;
        #pragma unroll
        for (int i = 0; i < 4; ++i) {
            int wl = wsum[i], wh = wsum[4 + i];
            total0 += wl;
            if (i < wv) { woff0 += wl; woff1lo += wh; }
        }
        sstart[tid] = woff0 + s0 - v0h;
        sstart[tid + 256] = total0 + woff1lo + s1 - v1h;
    }
    __syncthreads();

    #pragma unroll
    for (int it = 0; it < 16; ++it) {
        if (rrow[it] != 0xFFFFFFFFu) {
            int slot = sstart[rrow[it] >> 8] + (int)rslot[it];   // no atomics
            stageP[slot] = rpk[it];
            stageG[slot] = rrow[it];
        }
    }
    __syncthreads();

    int cnt = ntot - e0; if (cnt > CHUNK) cnt = CHUNK;
    for (int i = tid; i < cnt; i += 256) {
        unsigned gr = stageG[i];
        int bkt = gr >> 8;
        int dst = gdst[bkt] + (i - sstart[bkt]);
        recPacked[dst] = stageP[i];
        recRow[dst]   = (unsigned char)(gr & 255u);
    }
}

// -------- row_hist: block (b,y) histograms ONLY its segment -> hseg[b][y][256].
__global__ __launch_bounds__(256) void row_hist(
    const unsigned char* __restrict__ recRow, const int* __restrict__ bktBase,
    int* __restrict__ hseg)
{
    __shared__ int h[256];
    const int b = blockIdx.x, y = blockIdx.y, tid = threadIdx.x;
    const int start = bktBase[b], end = bktBase[b + 1];
    const int seg = (end - start + YSPLIT - 1) / YSPLIT;
    int myS = start + y * seg;  if (myS > end) myS = end;
    int myE = myS + seg;        if (myE > end) myE = end;

    h[tid] = 0;
    __syncthreads();
    for (int i = myS + tid; i < myE; i += 256)
        atomicAdd(&h[(int)recRow[i]], 1);
    __syncthreads();
    hseg[((size_t)b * YSPLIT + y) * 256 + tid] = h[tid];
}

// -------- row_sort2: merge segment histograms, scan, scatter own segment.
__global__ __launch_bounds__(256) void row_sort2(
    const unsigned* __restrict__ recPacked, const unsigned char* __restrict__ recRow,
    const int* __restrict__ bktBase, const int* __restrict__ hseg,
    int* __restrict__ ptr, unsigned* __restrict__ edges, int n_rows, int NB)
{
    __shared__ int sc[256], cur[256];
    const int b = blockIdx.x, y = blockIdx.y, tid = threadIdx.x;
    const int r0 = b << 8;
    const int start = bktBase[b], end = bktBase[b + 1];
    const int seg = (end - start + YSPLIT - 1) / YSPLIT;
    int myS = start + y * seg;  if (myS > end) myS = end;
    int myE = myS + seg;        if (myE > end) myE = end;

    int ht = 0, hb = 0;
    const int* hsb = hseg + (size_t)b * YSPLIT * 256 + tid;
    #pragma unroll
    for (int yy = 0; yy < YSPLIT; ++yy) {
        int v = hsb[yy * 256];
        ht += v;
        hb += (yy < y) ? v : 0;
    }

    sc[tid] = ht;
    __syncthreads();
    for (int o = 1; o < 256; o <<= 1) {
        int add = (tid >= o) ? sc[tid - o] : 0;
        __syncthreads();
        sc[tid] += add;
        __syncthreads();
    }
    const int excl = sc[tid] - ht;

    if (y == 0) {
        int grow = r0 + tid;
        if (grow < n_rows) ptr[grow] = start + excl;
        if (b == NB - 1 && tid == 0) ptr[n_rows] = end;
    }
    cur[tid] = excl + hb;
    __syncthreads();

    for (int i = myS + tid; i < myE; i += 256) {
        unsigned pk = recPacked[i];
        int r = (int)recRow[i];
        int dst = start + atomicAdd(&cur[r], 1);
        edges[dst] = pk;
    }
}

// -------- to_fp8: tab0 (bf16) -> tab8 (fp8 e4m3), 16 elems/thread (vectorized).
__global__ __launch_bounds__(256) void to_fp8(
    const unsigned short* __restrict__ tab0, unsigned char* __restrict__ tab8, int n)
{
    int i = blockIdx.x * 256 + threadIdx.x;
    if (i * 16 >= n) return;
    uint4 a = ((const uint4*)tab0)[i * 2];
    uint4 b = ((const uint4*)tab0)[i * 2 + 1];
    uint4 o;
    int t;
    t = __builtin_amdgcn_cvt_pk_fp8_f32(bf16lo(a.x), bf16hi(a.x), 0, false);
    o.x = (unsigned)__builtin_amdgcn_cvt_pk_fp8_f32(bf16lo(a.y), bf16hi(a.y), t, true);
    t = __builtin_amdgcn_cvt_pk_fp8_f32(bf16lo(a.z), bf16hi(a.z), 0, false);
    o.y = (unsigned)__builtin_amdgcn_cvt_pk_fp8_f32(bf16lo(a.w), bf16hi(a.w), t, true);
    t = __builtin_amdgcn_cvt_pk_fp8_f32(bf16lo(b.x), bf16hi(b.x), 0, false);
    o.z = (unsigned)__builtin_amdgcn_cvt_pk_fp8_f32(bf16lo(b.y), bf16hi(b.y), t, true);
    t = __builtin_amdgcn_cvt_pk_fp8_f32(bf16lo(b.z), bf16hi(b.z), 0, false);
    o.w = (unsigned)__builtin_amdgcn_cvt_pk_fp8_f32(bf16lo(b.w), bf16hi(b.w), t, true);
    ((uint4*)tab8)[i] = o;
}

// -------- Pull SpMM v5: fp8 gather + packed f32x2 accumulation.
// Fast path for full 64-edge batches (compile-time inner 8, fully unrolled);
// single ragged tail loop afterward.
__global__ __launch_bounds__(256) void pull_spmm(
    const unsigned short* __restrict__ tab0,
    const unsigned char* __restrict__ tab8,
    const int* __restrict__ ptr, const unsigned* __restrict__ edges,
    unsigned short* __restrict__ tabF, int S_, int n_rows)
{
    const int w = blockIdx.x * 4 + (threadIdx.x >> 6);
    if (w >= n_rows) return;
    const int lane = threadIdx.x & 63;
    const int g = lane >> 3;      // 8 edge-groups
    const int s = lane & 7;       // k-range 8s..8s+7

    const unsigned char* X8 = tab8 + ((w < S_) ? ((size_t)S_ << 6) : (size_t)0)
                                   + (size_t)s * 8;

    f32x2 acc2[4];
    #pragma unroll
    for (int i = 0; i < 4; ++i) acc2[i] = (f32x2){0.f, 0.f};

    int e = ptr[w];
    const int ee = ptr[w + 1];
    int len = ee - e;
    unsigned u = (lane < len) ? edges[e + lane] : 0u;

    // ---- fast path: full 64-edge batches, inner loop compile-time 8
    while (len >= 64) {
        unsigned un = (64 + lane < len) ? edges[e + 64 + lane] : 0u;  // prefetch
        #pragma unroll
        for (int jj = 0; jj < 8; ++jj) {
            unsigned uj = __shfl(u, jj * 8 + g);
            float v = __uint_as_float(uj << 16);     // low 16 = bf16 val
            f32x2 vv = {v, v};
            uint2 xv = *(const uint2*)(X8 + (((size_t)(uj >> 16)) << 6));
            acc2[0] = __builtin_amdgcn_cvt_pk_f32_fp8(xv.x, false) * vv + acc2[0];
            acc2[1] = __builtin_amdgcn_cvt_pk_f32_fp8(xv.x, true)  * vv + acc2[1];
            acc2[2] = __builtin_amdgcn_cvt_pk_f32_fp8(xv.y, false) * vv + acc2[2];
            acc2[3] = __builtin_amdgcn_cvt_pk_f32_fp8(xv.y, true)  * vv + acc2[3];
        }
        u = un;
        e += 64;
        len -= 64;
    }

    // ---- ragged tail (< 64 edges), u already holds edges[e+lane]
    if (len > 0) {
        int iters = (len + 7) >> 3;
        for (int jj = 0; jj < iters; ++jj) {
            unsigned uj = __shfl(u, jj * 8 + g);     // 0-word: col 0, val 0 -> harmless
            float v = __uint_as_float(uj << 16);
            f32x2 vv = {v, v};
            uint2 xv = *(const uint2*)(X8 + (((size_t)(uj >> 16)) << 6));
            acc2[0] = __builtin_amdgcn_cvt_pk_f32_fp8(xv.x, false) * vv + acc2[0];
            acc2[1] = __builtin_amdgcn_cvt_pk_f32_fp8(xv.x, true)  * vv + acc2[1];
            acc2[2] = __builtin_amdgcn_cvt_pk_f32_fp8(xv.y, false) * vv + acc2[2];
            acc2[3] = __builtin_amdgcn_cvt_pk_f32_fp8(xv.y, true)  * vv + acc2[3];
        }
    }

    #pragma unroll
    for (int i = 0; i < 4; ++i) {
        #pragma unroll
        for (int c = 0; c < 2; ++c) {
            acc2[i][c] += __shfl_xor(acc2[i][c], 8);
            acc2[i][c] += __shfl_xor(acc2[i][c], 16);
            acc2[i][c] += __shfl_xor(acc2[i][c], 32);
        }
    }

    if (g == 0) {
        const uint4 x0 = *(const uint4*)(tab0 + ((size_t)w << 6) + (size_t)s * 8);
        uint4 o;
        o.x = pack2bf16(acc2[0][0] + bf16lo(x0.x), acc2[0][1] + bf16hi(x0.x));
        o.y = pack2bf16(acc2[1][0] + bf16lo(x0.y), acc2[1][1] + bf16hi(x0.y));
        o.z = pack2bf16(acc2[2][0] + bf16lo(x0.z), acc2[2][1] + bf16hi(x0.z));
        o.w = pack2bf16(acc2[3][0] + bf16lo(x0.w), acc2[3][1] + bf16hi(x0.w));
        *(uint4*)(tabF + ((size_t)w << 6) + (size_t)s * 8) = o;
    }
}

// -------- MFMA tail: gather -> GEMM1(64x256x64) -> GEMM2(64x128x256) -> dot.
__global__ __launch_bounds__(256, 1) void tail_mlp(
    const unsigned short* __restrict__ tabF,
    const float* __restrict__ discW,
    const unsigned short* __restrict__ W1t, const float* __restrict__ b1,
    const unsigned short* __restrict__ W2t, const float* __restrict__ b2,
    const float* __restrict__ w3r, const float* __restrict__ b3,
    const float* __restrict__ kn, const int* __restrict__ stu_id,
    const int* __restrict__ exer_id, float* __restrict__ out, int S_, int B)
{
    __shared__ __align__(16) unsigned short xs_bf[64][72];   // 9.0 KB (pad: 2-way banks)
    __shared__ __align__(16) unsigned short h1s[64][264];    // 33.0 KB
    __shared__ __align__(16) unsigned short h2s[64][136];    // 17.0 KB
    __shared__ float b1s[256], b2s[128], w3s[128];
    const int tid = threadIdx.x;
    const int b0 = blockIdx.x * 64;

    b1s[tid] = b1[tid];
    if (tid < 128) { b2s[tid] = b2[tid]; w3s[tid] = w3r[tid]; }

    // ---- phase 0: x = disc*(stat-diff)/3*kn -> bf16 LDS tile (vectorized x4)
    #pragma unroll
    for (int i = 0; i < 4; ++i) {
        int e4 = (i * 256 + tid) * 4;
        int r = e4 >> 6, k0 = e4 & 63;
        int b = b0 + r;
        float4 x4 = make_float4(0.f, 0.f, 0.f, 0.f);
        if (b < B) {
            int sid = stu_id[b], eid = exer_id[b];
            float c = sigmoidf_(discW[eid]) * (1.f / 3.f);
            ushort4 st4 = *((const ushort4*)(tabF + (size_t)sid * 64 + k0));
            ushort4 df4 = *((const ushort4*)(tabF + ((size_t)(S_ + eid)) * 64 + k0));
            float4 kn4 = *((const float4*)(kn + (size_t)b * 64 + k0));
            x4.x = c * (bf16u_to_f(st4.x) - bf16u_to_f(df4.x)) * kn4.x;
            x4.y = c * (bf16u_to_f(st4.y) - bf16u_to_f(df4.y)) * kn4.y;
            x4.z = c * (bf16u_to_f(st4.z) - bf16u_to_f(df4.z)) * kn4.z;
            x4.w = c * (bf16u_to_f(st4.w) - bf16u_to_f(df4.w)) * kn4.w;
        }
        ushort4 xb;
        xb.x = f_to_bf16u(x4.x); xb.y = f_to_bf16u(x4.y);
        xb.z = f_to_bf16u(x4.z); xb.w = f_to_bf16u(x4.w);
        *((ushort4*)&xs_bf[r][k0]) = xb;
    }
    __syncthreads();

    const int w  = tid >> 6;
    const int l  = tid & 63;
    const int lr = l & 15;        // A row / B col / C col
    const int lg = l >> 4;        // k-group (8 contig k each)

    // ---- GEMM1: H1 = sigmoid(X[64x64] @ W1r[64x256] + b1)
    {
        short8v a0 = *(const short8v*)&xs_bf[16 * w + lr][lg * 8];
        short8v a1 = *(const short8v*)&xs_bf[16 * w + lr][32 + lg * 8];
        const unsigned short* w1base = W1t + (size_t)lr * 64 + lg * 8;
        #pragma unroll 4
        for (int n = 0; n < 16; ++n) {
            short8v bb0 = *(const short8v*)(w1base + n * 1024);
            short8v bb1 = *(const short8v*)(w1base + n * 1024 + 32);
            f32x4 acc = {0.f, 0.f, 0.f, 0.f};
            acc = __builtin_amdgcn_mfma_f32_16x16x32_bf16(a0, bb0, acc, 0, 0, 0);
            acc = __builtin_amdgcn_mfma_f32_16x16x32_bf16(a1, bb1, acc, 0, 0, 0);
            int col = n * 16 + lr;
            float bias = b1s[col];
            #pragma unroll
            for (int q = 0; q < 4; ++q)
                h1s[16 * w + lg * 4 + q][col] = f_to_bf16u(sigmoidf_(acc[q] + bias));
        }
    }
    __syncthreads();

    // ---- GEMM2: H2 = sigmoid(H1[64x256] @ W2r[256x128] + b2)
    {
        short8v ak[8];
        #pragma unroll
        for (int kk = 0; kk < 8; ++kk)
            ak[kk] = *(const short8v*)&h1s[16 * w + lr][kk * 32 + lg * 8];
        const unsigned short* w2base = W2t + (size_t)lr * 256 + lg * 8;
        #pragma unroll 2
        for (int n = 0; n < 8; ++n) {
            const unsigned short* bp = w2base + (size_t)n * 16 * 256;
            f32x4 acc = {0.f, 0.f, 0.f, 0.f};
            #pragma unroll
            for (int kk = 0; kk < 8; ++kk) {
                short8v bb = *(const short8v*)(bp + kk * 32);
                acc = __builtin_amdgcn_mfma_f32_16x16x32_bf16(ak[kk], bb, acc, 0, 0, 0);
            }
            int col = n * 16 + lr;
            float bias = b2s[col];
            #pragma unroll
            for (int q = 0; q < 4; ++q)
                h2s[16 * w + lg * 4 + q][col] = f_to_bf16u(sigmoidf_(acc[q] + bias));
        }
    }
    __syncthreads();

    // ---- GEMM3: out = sigmoid(H2 @ w3r + b3)   (64 rows, VALU)
    if (tid < 64) {
        int b = b0 + tid;
        if (b < B) {
            float acc = b3[0];
            const unsigned* h2r = (const unsigned*)&h2s[tid][0];
            #pragma unroll 8
            for (int jj = 0; jj < 64; ++jj) {
                unsigned hv = h2r[jj];
                acc += bf16lo(hv) * w3s[jj * 2 + 0] + bf16hi(hv) * w3s[jj * 2 + 1];
            }
            out[b] = sigmoidf_(acc);
        }
    }
}

extern "C" void kernel_launch(void* const* d_in, const int* in_sizes, int n_in,
                              void* d_out, int out_size, void* d_ws, size_t ws_size,
                              hipStream_t stream) {
    const float* stuW  = (const float*)d_in[0];
    const float* exerW = (const float*)d_in[1];
    const float* knowW = (const float*)d_in[2];
    const float* discW = (const float*)d_in[3];
    const float* W1 = (const float*)d_in[4];
    const float* b1 = (const float*)d_in[5];
    const float* W2 = (const float*)d_in[6];
    const float* b2 = (const float*)d_in[7];
    const float* W3 = (const float*)d_in[8];
    const float* b3 = (const float*)d_in[9];
    const int*   ui1_idx = (const int*)d_in[10];
    const float* ui1_val = (const float*)d_in[11];
    const int*   ui0_idx = (const int*)d_in[12];
    const float* ui0_val = (const float*)d_in[13];
    const int*   iu1_idx = (const int*)d_in[14];
    const float* iu1_val = (const float*)d_in[15];
    const int*   iu0_idx = (const int*)d_in[16];
    const float* iu0_val = (const float*)d_in[17];
    const float* kn      = (const float*)d_in[18];
    const int*   stu_id  = (const int*)d_in[19];
    const int*   exer_id = (const int*)d_in[20];
    float* out = (float*)d_out;

    const int S = in_sizes[0] / KDIM;
    const int E = in_sizes[1] / KDIM;
    const int B = in_sizes[19];
    const int n1 = in_sizes[11], n0 = in_sizes[13];
    const int m1 = in_sizes[15], m0 = in_sizes[17];
    const int ntot = n1 + n0 + m1 + m0;
    const int n_rows = S + E;
    const int NB = (n_rows + 255) / 256;            // 274
    const int nCnt = (ntot + CHUNK - 1) / CHUNK;    // 977

    const int nPrep = (256 * 64 + 128 * 256 + 128 + 255) / 256;   // 193
    const int nEmb  = (n_rows + 63) / 64;                          // 1094

    char* p = (char*)d_ws;
    unsigned short* tab0 = (unsigned short*)p; p += (size_t)n_rows * KDIM * 2;   // 8.96 MB
    unsigned* edges      = (unsigned*)p;       p += (size_t)ntot * 4;            // 16 MB (final)
    unsigned* recPacked  = (unsigned*)p;                                         // 16 MB (temp)
    // tabF aliases recPacked[0..]; tab8 aliases recPacked after tabF's extent.
    unsigned short* tabF = (unsigned short*)recPacked;
    unsigned char* tab8  = (unsigned char*)recPacked + (size_t)n_rows * KDIM * 2;
    p += (size_t)ntot * 4;
    unsigned char* recRow = (unsigned char*)p; p += (size_t)ntot;                // 4 MB (temp)
    int* ptr    = (int*)p;                     p += (size_t)(n_rows + 1) * 4;
    int* bktCnt = (int*)p;                     p += (size_t)NBPAD * 4;
    int* bktBase= (int*)p;                     p += (size_t)(NBPAD + 1) * 4;
    p = (char*)(((uintptr_t)p + 255) & ~(uintptr_t)255);     // 16B+ align for vec loads
    unsigned short* W1t = (unsigned short*)p;  p += 256 * 64 * 2;                // 32 KB
    unsigned short* W2t = (unsigned short*)p;  p += 128 * 256 * 2;               // 64 KB
    float* w3r          = (float*)p;           p += 128 * 4;
    p = (char*)(((uintptr_t)p + 255) & ~(uintptr_t)255);
    int* hseg           = (int*)p;             p += (size_t)NB * YSPLIT * 256 * 4; // 2.24 MB
    p = (char*)(((uintptr_t)p + 255) & ~(uintptr_t)255);
    int* hcb            = (int*)p;             p += (size_t)NB * nCnt * 4;         // 1.07 MB

    front_fused<<<nPrep + nEmb + nCnt, 256, 0, stream>>>(
        stuW, exerW, knowW, W1, W2, W3,
        ui1_idx, ui0_idx, iu1_idx, iu0_idx,
        n1, n0, m1, S, n_rows, ntot, NB,
        tab0, W1t, W2t, w3r,
        hcb, nCnt, nPrep, nEmb);

    col_scan<<<NB, 256, 0, stream>>>(hcb, bktCnt, nCnt);

    scan_tiny<<<1, 256, 0, stream>>>(bktCnt, bktBase, NB);

    bin_scatter<<<nCnt, 256, 0, stream>>>(
        ui1_idx, ui1_val, ui0_idx, ui0_val, iu1_idx, iu1_val, iu0_idx, iu0_val,
        n1, n0, m1, m0, S, bktBase, hcb, nCnt, recPacked, recRow, ntot, NB);

    row_hist<<<dim3(NB, YSPLIT), 256, 0, stream>>>(recRow, bktBase, hseg);

    row_sort2<<<dim3(NB, YSPLIT), 256, 0, stream>>>(recPacked, recRow, bktBase, hseg,
                                                    ptr, edges, n_rows, NB);

    // tab8 lives in recPacked's region (dead after row_sort2, past tabF extent)
    to_fp8<<<(n_rows * KDIM / 16 + 255) / 256, 256, 0, stream>>>(tab0, tab8, n_rows * KDIM);

    pull_spmm<<<(n_rows + 3) / 4, 256, 0, stream>>>(tab0, tab8, ptr, edges,
                                                    tabF, S, n_rows);

    tail_mlp<<<(B + 63) / 64, 256, 0, stream>>>(tabF, discW,
                                                W1t, b1, W2t, b2, w3r, b3,
                                                kn, stu_id, exer_id, out, S, B);
}

// Round 21
// 173.689 us; speedup vs baseline: 1.4059x; 1.0461x over previous
//
#include <hip/hip_runtime.h>

#define KDIM 64
#define NBPAD 512          // padded bucket-array size (NB = 274 here)
#define CHUNK 4096         // records per bin_scatter / count block
#define YSPLIT 8           // row sort segments per bucket

typedef __attribute__((ext_vector_type(8))) short short8v;   // 8 bf16 (4 VGPRs)
typedef __attribute__((ext_vector_type(4))) float f32x4;     // MFMA acc
typedef __attribute__((ext_vector_type(2))) float f32x2;     // fp8 cvt result

__device__ __forceinline__ float bf16u_to_f(unsigned short u) {
    return __uint_as_float(((unsigned)u) << 16);
}
__device__ __forceinline__ float bf16lo(unsigned u) {
    return __uint_as_float(u << 16);
}
__device__ __forceinline__ float bf16hi(unsigned u) {
    return __uint_as_float(u & 0xFFFF0000u);
}
__device__ __forceinline__ unsigned short f_to_bf16u(float f) {
    unsigned b = __float_as_uint(f);
    b += 0x7FFF + ((b >> 16) & 1);          // round-to-nearest-even
    return (unsigned short)(b >> 16);
}
__device__ __forceinline__ unsigned pack2bf16(float lo, float hi) {
    return ((unsigned)f_to_bf16u(lo)) | (((unsigned)f_to_bf16u(hi)) << 16);
}
__device__ __forceinline__ float sigmoidf_(float x) {
    return 1.f / (1.f + __expf(-x));
}

// Unified row space over the 4 concatenated edge lists:
// [0,S) students (ui1,ui0), [S,S+E) exercises (iu1,iu0).
__device__ __forceinline__ int dec_row(int e,
    const int* __restrict__ i1, const int* __restrict__ i0,
    const int* __restrict__ j1, const int* __restrict__ j0,
    int n1, int n0, int m1, int S_)
{
    if (e < n1) return i1[e];
    e -= n1;
    if (e < n0) return i0[e];
    e -= n0;
    if (e < m1) return S_ + j1[e];
    e -= m1;
    return S_ + j0[e];
}

__device__ __forceinline__ void dec_full(int e,
    const int* __restrict__ i1, const float* __restrict__ v1,
    const int* __restrict__ i0, const float* __restrict__ v0,
    const int* __restrict__ j1, const float* __restrict__ w1,
    const int* __restrict__ j0, const float* __restrict__ w0,
    int n1, int n0, int m1, int m0, int S_,
    unsigned& row, unsigned& pk)
{
    int col; float v;
    if (e < n1) { row = (unsigned)i1[e]; col = i1[n1 + e]; v = v1[e]; }
    else if (e < n1 + n0) { int le = e - n1; row = (unsigned)i0[le]; col = i0[n0 + le]; v = v0[le]; }
    else if (e < n1 + n0 + m1) { int le = e - n1 - n0; row = (unsigned)(S_ + j1[le]); col = j1[m1 + le]; v = w1[le]; }
    else { int le = e - n1 - n0 - m1; row = (unsigned)(S_ + j0[le]); col = j0[m0 + le]; v = w0[le]; }
    pk = ((unsigned)col << 16) | (unsigned)f_to_bf16u(v);
}

// -------- front_fused: [prep weights | embed MFMA | per-chunk bucket hist]
// Three independent roles by blockIdx range; NO global atomics anywhere.
__global__ __launch_bounds__(256) void front_fused(
    const float* __restrict__ stuW, const float* __restrict__ exerW,
    const float* __restrict__ knowW,
    const float* __restrict__ W1, const float* __restrict__ W2,
    const float* __restrict__ W3,
    const int* __restrict__ i1, const int* __restrict__ i0,
    const int* __restrict__ j1, const int* __restrict__ j0,
    int n1, int n0, int m1, int S_, int n_rows, int ntot, int NB,
    unsigned short* __restrict__ tab0,
    unsigned short* __restrict__ W1t, unsigned short* __restrict__ W2t,
    float* __restrict__ w3r,
    int* __restrict__ hcb, int nCnt,
    int nPrep, int nEmb)
{
    __shared__ int shmem[NBPAD];
    const int tid = threadIdx.x;
    int bx = blockIdx.x;

    // ---------------- role 1: weight prep (W1t/W2t/w3r) ----------------
    if (bx < nPrep) {
        int i = bx * 256 + tid;
        if (i < 256 * 64) {                     // W1t[n][k] = relu(W1[k][n])
            int n = i >> 6, k = i & 63;
            W1t[i] = f_to_bf16u(fmaxf(W1[k * 256 + n], 0.f));
            return;
        }
        int j = i - 256 * 64;
        if (j < 128 * 256) {                    // W2t[n][k] = relu(W2[k][n])
            int n = j >> 8, k = j & 255;
            W2t[j] = f_to_bf16u(fmaxf(W2[k * 128 + n], 0.f));
            return;
        }
        int l = j - 128 * 256;
        if (l < 128) w3r[l] = fmaxf(W3[l], 0.f);
        return;
    }
    bx -= nPrep;

    // ---------------- role 2: embed MFMA (64 rows/block) ----------------
    if (bx < nEmb) {
        const int w = tid >> 6, l = tid & 63;
        const int lr = l & 15, lg = l >> 4;
        const int r0 = bx * 64 + 16 * w;

        const int arow = min(r0 + lr, n_rows - 1);
        const float* a = (arow < S_) ? (stuW + (size_t)arow * KDIM)
                                     : (exerW + (size_t)(arow - S_) * KDIM);
        float4 v0 = *((const float4*)(a + lg * 8));
        float4 v1 = *((const float4*)(a + lg * 8 + 4));
        float4 v2 = *((const float4*)(a + 32 + lg * 8));
        float4 v3 = *((const float4*)(a + 32 + lg * 8 + 4));
        union { unsigned u[4]; short8v s; } A0, A1;
        A0.u[0] = pack2bf16(v0.x, v0.y); A0.u[1] = pack2bf16(v0.z, v0.w);
        A0.u[2] = pack2bf16(v1.x, v1.y); A0.u[3] = pack2bf16(v1.z, v1.w);
        A1.u[0] = pack2bf16(v2.x, v2.y); A1.u[1] = pack2bf16(v2.z, v2.w);
        A1.u[2] = pack2bf16(v3.x, v3.y); A1.u[3] = pack2bf16(v3.z, v3.w);

        #pragma unroll
        for (int n = 0; n < 4; ++n) {
            const float* kb = knowW + (size_t)(n * 16 + lr) * KDIM + lg * 8;
            float4 b0f = *(const float4*)kb;
            float4 b0g = *(const float4*)(kb + 4);
            float4 b1f = *(const float4*)(kb + 32);
            float4 b1g = *(const float4*)(kb + 36);
            union { unsigned u[4]; short8v s; } B0, B1;
            B0.u[0] = pack2bf16(b0f.x, b0f.y); B0.u[1] = pack2bf16(b0f.z, b0f.w);
            B0.u[2] = pack2bf16(b0g.x, b0g.y); B0.u[3] = pack2bf16(b0g.z, b0g.w);
            B1.u[0] = pack2bf16(b1f.x, b1f.y); B1.u[1] = pack2bf16(b1f.z, b1f.w);
            B1.u[2] = pack2bf16(b1g.x, b1g.y); B1.u[3] = pack2bf16(b1g.z, b1g.w);
            f32x4 acc = {0.f, 0.f, 0.f, 0.f};
            acc = __builtin_amdgcn_mfma_f32_16x16x32_bf16(A0.s, B0.s, acc, 0, 0, 0);
            acc = __builtin_amdgcn_mfma_f32_16x16x32_bf16(A1.s, B1.s, acc, 0, 0, 0);
            #pragma unroll
            for (int q = 0; q < 4; ++q) {
                int srow = r0 + lg * 4 + q;
                if (srow < n_rows)
                    tab0[(size_t)srow * KDIM + n * 16 + lr] = f_to_bf16u(sigmoidf_(acc[q]));
            }
        }
        return;
    }
    bx -= nEmb;

    // ---------------- role 3: per-chunk bucket histogram ----------------
    for (int i = tid; i < NBPAD; i += 256) shmem[i] = 0;
    __syncthreads();
    const int e0 = bx * CHUNK;
    #pragma unroll
    for (int it = 0; it < 16; ++it) {
        int e = e0 + it * 256 + tid;
        if (e < ntot) atomicAdd(&shmem[dec_row(e, i1, i0, j1, j0, n1, n0, m1, S_) >> 8], 1);
    }
    __syncthreads();
    for (int b = tid; b < NB; b += 256)
        hcb[(size_t)b * nCnt + bx] = shmem[b];     // plain store, no atomics
}

// -------- col_scan: per bucket b, exclusive prefix over chunks (in place);
// total -> bktCnt[b]. Contiguous row reads; 274 blocks.
__global__ __launch_bounds__(256) void col_scan(
    int* __restrict__ hcb, int* __restrict__ bktCnt, int nCnt)
{
    __shared__ int sc[256];
    const int b = blockIdx.x, tid = threadIdx.x;
    int* row = hcb + (size_t)b * nCnt;
    int carry = 0;
    for (int t0 = 0; t0 < nCnt; t0 += 256) {
        int idx = t0 + tid;
        int v = (idx < nCnt) ? row[idx] : 0;
        sc[tid] = v;
        __syncthreads();
        for (int o = 1; o < 256; o <<= 1) {
            int a = (tid >= o) ? sc[tid - o] : 0;
            __syncthreads();
            sc[tid] += a;
            __syncthreads();
        }
        if (idx < nCnt) row[idx] = carry + sc[tid] - v;   // exclusive
        carry += sc[255];
        __syncthreads();
    }
    if (tid == 0) bktCnt[b] = carry;
}

// -------- exclusive scan of NB bucket counts -> bktBase
__global__ __launch_bounds__(256) void scan_tiny(
    const int* __restrict__ bktCnt, int* __restrict__ bktBase, int NB)
{
    __shared__ int s[NBPAD + 1];
    for (int i = threadIdx.x; i < NB; i += 256) s[i] = bktCnt[i];
    __syncthreads();
    if (threadIdx.x == 0) {
        int acc = 0;
        for (int b = 0; b < NB; ++b) { int c = s[b]; s[b] = acc; acc += c; }
        s[NB] = acc;
    }
    __syncthreads();
    for (int i = threadIdx.x; i <= NB; i += 256) bktBase[i] = s[i];
}

// -------- binned scatter v5: NO global atomics — gdst from precomputed
// deterministic chunk offsets (bktBase[b] + hcb[b][bx]). Single LDS atomic
// per record (hist return value = slot), shfl 512-prefix.
__global__ __launch_bounds__(256) void bin_scatter(
    const int* __restrict__ i1, const float* __restrict__ v1,
    const int* __restrict__ i0, const float* __restrict__ v0,
    const int* __restrict__ j1, const float* __restrict__ w1,
    const int* __restrict__ j0, const float* __restrict__ w0,
    int n1, int n0, int m1, int m0, int S_,
    const int* __restrict__ bktBase, const int* __restrict__ hcb, int nCnt,
    unsigned* __restrict__ recPacked, unsigned char* __restrict__ recRow,
    int ntot, int NB)
{
    __shared__ int h[NBPAD], sstart[NBPAD], gdst[NBPAD];
    __shared__ int wsum[8];
    __shared__ unsigned stageP[CHUNK];
    __shared__ unsigned stageG[CHUNK];       // (bkt<<8)|rowLocal
    const int tid = threadIdx.x;
    const int bx = blockIdx.x;
    const int e0 = bx * CHUNK;

    for (int i = tid; i < NBPAD; i += 256) h[i] = 0;
    // deterministic global destinations (no atomics) — issue loads early
    if (tid < NB) gdst[tid] = bktBase[tid] + hcb[(size_t)tid * nCnt + bx];
    if (tid + 256 < NB) gdst[tid + 256] = bktBase[tid + 256] + hcb[(size_t)(tid + 256) * nCnt + bx];
    __syncthreads();

    unsigned rrow[16], rpk[16];
    unsigned short rslot[16];
    #pragma unroll
    for (int it = 0; it < 16; ++it) {
        int e = e0 + it * 256 + tid;
        if (e < ntot) {
            dec_full(e, i1, v1, i0, v0, j1, w1, j0, w0, n1, n0, m1, m0, S_,
                     rrow[it], rpk[it]);
            rslot[it] = (unsigned short)atomicAdd(&h[rrow[it] >> 8], 1);
        } else {
            rrow[it] = 0xFFFFFFFFu;
        }
    }
    __syncthreads();

    {   // exclusive prefix over 512 buckets: per-wave shfl scans, one exchange.
        const int wv = tid >> 6, ln = tid & 63;
        int v0h = h[tid];
        int v1h = h[tid + 256];
        int s0 = v0h, s1 = v1h;
        #pragma unroll
        for (int o = 1; o < 64; o <<= 1) {
            int t0 = __shfl_up(s0, o);
            int t1 = __shfl_up(s1, o);
            if (ln >= o) { s0 += t0; s1 += t1; }
        }
        if (ln == 63) { wsum[wv] = s0; wsum[4 + wv] = s1; }
        __syncthreads();
        int woff0 = 0, total0 = 0, woff1lo = 0;
        #pragma unroll
        for (int i = 0; i < 4; ++i) {
            int wl = wsum[i], wh = wsum[4 + i];
            total0 += wl;
            if (i < wv) { woff0 += wl; woff1lo += wh; }
        }
        sstart[tid] = woff0 + s0 - v0h;
        sstart[tid + 256] = total0 + woff1lo + s1 - v1h;
    }
    __syncthreads();

    #pragma unroll
    for (int it = 0; it < 16; ++it) {
        if (rrow[it] != 0xFFFFFFFFu) {
            int slot = sstart[rrow[it] >> 8] + (int)rslot[it];   // no atomics
            stageP[slot] = rpk[it];
            stageG[slot] = rrow[it];
        }
    }
    __syncthreads();

    int cnt = ntot - e0; if (cnt > CHUNK) cnt = CHUNK;
    for (int i = tid; i < cnt; i += 256) {
        unsigned gr = stageG[i];
        int bkt = gr >> 8;
        int dst = gdst[bkt] + (i - sstart[bkt]);
        recPacked[dst] = stageP[i];
        recRow[dst]   = (unsigned char)(gr & 255u);
    }
}

// -------- row_hist: block (b,y) histograms ONLY its segment -> hseg[b][y][256].
__global__ __launch_bounds__(256) void row_hist(
    const unsigned char* __restrict__ recRow, const int* __restrict__ bktBase,
    int* __restrict__ hseg)
{
    __shared__ int h[256];
    const int b = blockIdx.x, y = blockIdx.y, tid = threadIdx.x;
    const int start = bktBase[b], end = bktBase[b + 1];
    const int seg = (end - start + YSPLIT - 1) / YSPLIT;
    int myS = start + y * seg;  if (myS > end) myS = end;
    int myE = myS + seg;        if (myE > end) myE = end;

    h[tid] = 0;
    __syncthreads();
    for (int i = myS + tid; i < myE; i += 256)
        atomicAdd(&h[(int)recRow[i]], 1);
    __syncthreads();
    hseg[((size_t)b * YSPLIT + y) * 256 + tid] = h[tid];
}

// -------- row_sort2: merge segment histograms, scan, scatter own segment.
__global__ __launch_bounds__(256) void row_sort2(
    const unsigned* __restrict__ recPacked, const unsigned char* __restrict__ recRow,
    const int* __restrict__ bktBase, const int* __restrict__ hseg,
    int* __restrict__ ptr, unsigned* __restrict__ edges, int n_rows, int NB)
{
    __shared__ int sc[256], cur[256];
    const int b = blockIdx.x, y = blockIdx.y, tid = threadIdx.x;
    const int r0 = b << 8;
    const int start = bktBase[b], end = bktBase[b + 1];
    const int seg = (end - start + YSPLIT - 1) / YSPLIT;
    int myS = start + y * seg;  if (myS > end) myS = end;
    int myE = myS + seg;        if (myE > end) myE = end;

    int ht = 0, hb = 0;
    const int* hsb = hseg + (size_t)b * YSPLIT * 256 + tid;
    #pragma unroll
    for (int yy = 0; yy < YSPLIT; ++yy) {
        int v = hsb[yy * 256];
        ht += v;
        hb += (yy < y) ? v : 0;
    }

    sc[tid] = ht;
    __syncthreads();
    for (int o = 1; o < 256; o <<= 1) {
        int add = (tid >= o) ? sc[tid - o] : 0;
        __syncthreads();
        sc[tid] += add;
        __syncthreads();
    }
    const int excl = sc[tid] - ht;

    if (y == 0) {
        int grow = r0 + tid;
        if (grow < n_rows) ptr[grow] = start + excl;
        if (b == NB - 1 && tid == 0) ptr[n_rows] = end;
    }
    cur[tid] = excl + hb;
    __syncthreads();

    for (int i = myS + tid; i < myE; i += 256) {
        unsigned pk = recPacked[i];
        int r = (int)recRow[i];
        int dst = start + atomicAdd(&cur[r], 1);
        edges[dst] = pk;
    }
}

// -------- to_fp8: tab0 (bf16) -> tab8 (fp8 e4m3), 16 elems/thread (vectorized).
__global__ __launch_bounds__(256) void to_fp8(
    const unsigned short* __restrict__ tab0, unsigned char* __restrict__ tab8, int n)
{
    int i = blockIdx.x * 256 + threadIdx.x;
    if (i * 16 >= n) return;
    uint4 a = ((const uint4*)tab0)[i * 2];
    uint4 b = ((const uint4*)tab0)[i * 2 + 1];
    uint4 o;
    int t;
    t = __builtin_amdgcn_cvt_pk_fp8_f32(bf16lo(a.x), bf16hi(a.x), 0, false);
    o.x = (unsigned)__builtin_amdgcn_cvt_pk_fp8_f32(bf16lo(a.y), bf16hi(a.y), t, true);
    t = __builtin_amdgcn_cvt_pk_fp8_f32(bf16lo(a.z), bf16hi(a.z), 0, false);
    o.y = (unsigned)__builtin_amdgcn_cvt_pk_fp8_f32(bf16lo(a.w), bf16hi(a.w), t, true);
    t = __builtin_amdgcn_cvt_pk_fp8_f32(bf16lo(b.x), bf16hi(b.x), 0, false);
    o.z = (unsigned)__builtin_amdgcn_cvt_pk_fp8_f32(bf16lo(b.y), bf16hi(b.y), t, true);
    t = __builtin_amdgcn_cvt_pk_fp8_f32(bf16lo(b.z), bf16hi(b.z), 0, false);
    o.w = (unsigned)__builtin_amdgcn_cvt_pk_fp8_f32(bf16lo(b.w), bf16hi(b.w), t, true);
    ((uint4*)tab8)[i] = o;
}

// -------- Pull SpMM v6: fp8 gather + packed f32x2 accumulation.
// Single fully-unrolled 8-iteration body per 64-edge batch; padded edge
// slots carry u=0 (col 0, val 0 -> adds 0), so no tail path exists and all
// 8 gathers of a batch issue in flight (no runtime-trip inner loop).
__global__ __launch_bounds__(256) void pull_spmm(
    const unsigned short* __restrict__ tab0,
    const unsigned char* __restrict__ tab8,
    const int* __restrict__ ptr, const unsigned* __restrict__ edges,
    unsigned short* __restrict__ tabF, int S_, int n_rows)
{
    const int w = blockIdx.x * 4 + (threadIdx.x >> 6);
    if (w >= n_rows) return;
    const int lane = threadIdx.x & 63;
    const int g = lane >> 3;      // 8 edge-groups
    const int s = lane & 7;       // k-range 8s..8s+7

    const unsigned char* X8 = tab8 + ((w < S_) ? ((size_t)S_ << 6) : (size_t)0)
                                   + (size_t)s * 8;

    f32x2 acc2[4];
    #pragma unroll
    for (int i = 0; i < 4; ++i) acc2[i] = (f32x2){0.f, 0.f};

    int e = ptr[w];
    const int ee = ptr[w + 1];
    int len = ee - e;
    unsigned u = (lane < len) ? edges[e + lane] : 0u;

    while (len > 0) {
        unsigned un = (64 + lane < len) ? edges[e + 64 + lane] : 0u;  // prefetch
        #pragma unroll
        for (int jj = 0; jj < 8; ++jj) {
            unsigned uj = __shfl(u, jj * 8 + g);     // 0-word: col 0, val 0 -> adds 0
            float v = __uint_as_float(uj << 16);     // low 16 = bf16 val
            f32x2 vv = {v, v};
            uint2 xv = *(const uint2*)(X8 + (((size_t)(uj >> 16)) << 6));
            acc2[0] = __builtin_amdgcn_cvt_pk_f32_fp8(xv.x, false) * vv + acc2[0];
            acc2[1] = __builtin_amdgcn_cvt_pk_f32_fp8(xv.x, true)  * vv + acc2[1];
            acc2[2] = __builtin_amdgcn_cvt_pk_f32_fp8(xv.y, false) * vv + acc2[2];
            acc2[3] = __builtin_amdgcn_cvt_pk_f32_fp8(xv.y, true)  * vv + acc2[3];
        }
        u = un;
        e += 64;
        len -= 64;
    }

    #pragma unroll
    for (int i = 0; i < 4; ++i) {
        #pragma unroll
        for (int c = 0; c < 2; ++c) {
            acc2[i][c] += __shfl_xor(acc2[i][c], 8);
            acc2[i][c] += __shfl_xor(acc2[i][c], 16);
            acc2[i][c] += __shfl_xor(acc2[i][c], 32);
        }
    }

    if (g == 0) {
        const uint4 x0 = *(const uint4*)(tab0 + ((size_t)w << 6) + (size_t)s * 8);
        uint4 o;
        o.x = pack2bf16(acc2[0][0] + bf16lo(x0.x), acc2[0][1] + bf16hi(x0.x));
        o.y = pack2bf16(acc2[1][0] + bf16lo(x0.y), acc2[1][1] + bf16hi(x0.y));
        o.z = pack2bf16(acc2[2][0] + bf16lo(x0.z), acc2[2][1] + bf16hi(x0.z));
        o.w = pack2bf16(acc2[3][0] + bf16lo(x0.w), acc2[3][1] + bf16hi(x0.w));
        *(uint4*)(tabF + ((size_t)w << 6) + (size_t)s * 8) = o;
    }
}

// -------- MFMA tail: gather -> GEMM1(64x256x64) -> GEMM2(64x128x256) -> dot.
__global__ __launch_bounds__(256, 1) void tail_mlp(
    const unsigned short* __restrict__ tabF,
    const float* __restrict__ discW,
    const unsigned short* __restrict__ W1t, const float* __restrict__ b1,
    const unsigned short* __restrict__ W2t, const float* __restrict__ b2,
    const float* __restrict__ w3r, const float* __restrict__ b3,
    const float* __restrict__ kn, const int* __restrict__ stu_id,
    const int* __restrict__ exer_id, float* __restrict__ out, int S_, int B)
{
    __shared__ __align__(16) unsigned short xs_bf[64][72];   // 9.0 KB (pad: 2-way banks)
    __shared__ __align__(16) unsigned short h1s[64][264];    // 33.0 KB
    __shared__ __align__(16) unsigned short h2s[64][136];    // 17.0 KB
    __shared__ float b1s[256], b2s[128], w3s[128];
    const int tid = threadIdx.x;
    const int b0 = blockIdx.x * 64;

    b1s[tid] = b1[tid];
    if (tid < 128) { b2s[tid] = b2[tid]; w3s[tid] = w3r[tid]; }

    // ---- phase 0: x = disc*(stat-diff)/3*kn -> bf16 LDS tile (vectorized x4)
    #pragma unroll
    for (int i = 0; i < 4; ++i) {
        int e4 = (i * 256 + tid) * 4;
        int r = e4 >> 6, k0 = e4 & 63;
        int b = b0 + r;
        float4 x4 = make_float4(0.f, 0.f, 0.f, 0.f);
        if (b < B) {
            int sid = stu_id[b], eid = exer_id[b];
            float c = sigmoidf_(discW[eid]) * (1.f / 3.f);
            ushort4 st4 = *((const ushort4*)(tabF + (size_t)sid * 64 + k0));
            ushort4 df4 = *((const ushort4*)(tabF + ((size_t)(S_ + eid)) * 64 + k0));
            float4 kn4 = *((const float4*)(kn + (size_t)b * 64 + k0));
            x4.x = c * (bf16u_to_f(st4.x) - bf16u_to_f(df4.x)) * kn4.x;
            x4.y = c * (bf16u_to_f(st4.y) - bf16u_to_f(df4.y)) * kn4.y;
            x4.z = c * (bf16u_to_f(st4.z) - bf16u_to_f(df4.z)) * kn4.z;
            x4.w = c * (bf16u_to_f(st4.w) - bf16u_to_f(df4.w)) * kn4.w;
        }
        ushort4 xb;
        xb.x = f_to_bf16u(x4.x); xb.y = f_to_bf16u(x4.y);
        xb.z = f_to_bf16u(x4.z); xb.w = f_to_bf16u(x4.w);
        *((ushort4*)&xs_bf[r][k0]) = xb;
    }
    __syncthreads();

    const int w  = tid >> 6;
    const int l  = tid & 63;
    const int lr = l & 15;        // A row / B col / C col
    const int lg = l >> 4;        // k-group (8 contig k each)

    // ---- GEMM1: H1 = sigmoid(X[64x64] @ W1r[64x256] + b1)
    {
        short8v a0 = *(const short8v*)&xs_bf[16 * w + lr][lg * 8];
        short8v a1 = *(const short8v*)&xs_bf[16 * w + lr][32 + lg * 8];
        const unsigned short* w1base = W1t + (size_t)lr * 64 + lg * 8;
        #pragma unroll 4
        for (int n = 0; n < 16; ++n) {
            short8v bb0 = *(const short8v*)(w1base + n * 1024);
            short8v bb1 = *(const short8v*)(w1base + n * 1024 + 32);
            f32x4 acc = {0.f, 0.f, 0.f, 0.f};
            acc = __builtin_amdgcn_mfma_f32_16x16x32_bf16(a0, bb0, acc, 0, 0, 0);
            acc = __builtin_amdgcn_mfma_f32_16x16x32_bf16(a1, bb1, acc, 0, 0, 0);
            int col = n * 16 + lr;
            float bias = b1s[col];
            #pragma unroll
            for (int q = 0; q < 4; ++q)
                h1s[16 * w + lg * 4 + q][col] = f_to_bf16u(sigmoidf_(acc[q] + bias));
        }
    }
    __syncthreads();

    // ---- GEMM2: H2 = sigmoid(H1[64x256] @ W2r[256x128] + b2)
    {
        short8v ak[8];
        #pragma unroll
        for (int kk = 0; kk < 8; ++kk)
            ak[kk] = *(const short8v*)&h1s[16 * w + lr][kk * 32 + lg * 8];
        const unsigned short* w2base = W2t + (size_t)lr * 256 + lg * 8;
        #pragma unroll 2
        for (int n = 0; n < 8; ++n) {
            const unsigned short* bp = w2base + (size_t)n * 16 * 256;
            f32x4 acc = {0.f, 0.f, 0.f, 0.f};
            #pragma unroll
            for (int kk = 0; kk < 8; ++kk) {
                short8v bb = *(const short8v*)(bp + kk * 32);
                acc = __builtin_amdgcn_mfma_f32_16x16x32_bf16(ak[kk], bb, acc, 0, 0, 0);
            }
            int col = n * 16 + lr;
            float bias = b2s[col];
            #pragma unroll
            for (int q = 0; q < 4; ++q)
                h2s[16 * w + lg * 4 + q][col] = f_to_bf16u(sigmoidf_(acc[q] + bias));
        }
    }
    __syncthreads();

    // ---- GEMM3: out = sigmoid(H2 @ w3r + b3)   (64 rows, VALU)
    if (tid < 64) {
        int b = b0 + tid;
        if (b < B) {
            float acc = b3[0];
            const unsigned* h2r = (const unsigned*)&h2s[tid][0];
            #pragma unroll 8
            for (int jj = 0; jj < 64; ++jj) {
                unsigned hv = h2r[jj];
                acc += bf16lo(hv) * w3s[jj * 2 + 0] + bf16hi(hv) * w3s[jj * 2 + 1];
            }
            out[b] = sigmoidf_(acc);
        }
    }
}

extern "C" void kernel_launch(void* const* d_in, const int* in_sizes, int n_in,
                              void* d_out, int out_size, void* d_ws, size_t ws_size,
                              hipStream_t stream) {
    const float* stuW  = (const float*)d_in[0];
    const float* exerW = (const float*)d_in[1];
    const float* knowW = (const float*)d_in[2];
    const float* discW = (const float*)d_in[3];
    const float* W1 = (const float*)d_in[4];
    const float* b1 = (const float*)d_in[5];
    const float* W2 = (const float*)d_in[6];
    const float* b2 = (const float*)d_in[7];
    const float* W3 = (const float*)d_in[8];
    const float* b3 = (const float*)d_in[9];
    const int*   ui1_idx = (const int*)d_in[10];
    const float* ui1_val = (const float*)d_in[11];
    const int*   ui0_idx = (const int*)d_in[12];
    const float* ui0_val = (const float*)d_in[13];
    const int*   iu1_idx = (const int*)d_in[14];
    const float* iu1_val = (const float*)d_in[15];
    const int*   iu0_idx = (const int*)d_in[16];
    const float* iu0_val = (const float*)d_in[17];
    const float* kn      = (const float*)d_in[18];
    const int*   stu_id  = (const int*)d_in[19];
    const int*   exer_id = (const int*)d_in[20];
    float* out = (float*)d_out;

    const int S = in_sizes[0] / KDIM;
    const int E = in_sizes[1] / KDIM;
    const int B = in_sizes[19];
    const int n1 = in_sizes[11], n0 = in_sizes[13];
    const int m1 = in_sizes[15], m0 = in_sizes[17];
    const int ntot = n1 + n0 + m1 + m0;
    const int n_rows = S + E;
    const int NB = (n_rows + 255) / 256;            // 274
    const int nCnt = (ntot + CHUNK - 1) / CHUNK;    // 977

    const int nPrep = (256 * 64 + 128 * 256 + 128 + 255) / 256;   // 193
    const int nEmb  = (n_rows + 63) / 64;                          // 1094

    char* p = (char*)d_ws;
    unsigned short* tab0 = (unsigned short*)p; p += (size_t)n_rows * KDIM * 2;   // 8.96 MB
    unsigned* edges      = (unsigned*)p;       p += (size_t)ntot * 4;            // 16 MB (final)
    unsigned* recPacked  = (unsigned*)p;                                         // 16 MB (temp)
    // tabF aliases recPacked[0..]; tab8 aliases recPacked after tabF's extent.
    unsigned short* tabF = (unsigned short*)recPacked;
    unsigned char* tab8  = (unsigned char*)recPacked + (size_t)n_rows * KDIM * 2;
    p += (size_t)ntot * 4;
    unsigned char* recRow = (unsigned char*)p; p += (size_t)ntot;                // 4 MB (temp)
    int* ptr    = (int*)p;                     p += (size_t)(n_rows + 1) * 4;
    int* bktCnt = (int*)p;                     p += (size_t)NBPAD * 4;
    int* bktBase= (int*)p;                     p += (size_t)(NBPAD + 1) * 4;
    p = (char*)(((uintptr_t)p + 255) & ~(uintptr_t)255);     // 16B+ align for vec loads
    unsigned short* W1t = (unsigned short*)p;  p += 256 * 64 * 2;                // 32 KB
    unsigned short* W2t = (unsigned short*)p;  p += 128 * 256 * 2;               // 64 KB
    float* w3r          = (float*)p;           p += 128 * 4;
    p = (char*)(((uintptr_t)p + 255) & ~(uintptr_t)255);
    int* hseg           = (int*)p;             p += (size_t)NB * YSPLIT * 256 * 4; // 2.24 MB
    p = (char*)(((uintptr_t)p + 255) & ~(uintptr_t)255);
    int* hcb            = (int*)p;             p += (size_t)NB * nCnt * 4;         // 1.07 MB

    front_fused<<<nPrep + nEmb + nCnt, 256, 0, stream>>>(
        stuW, exerW, knowW, W1, W2, W3,
        ui1_idx, ui0_idx, iu1_idx, iu0_idx,
        n1, n0, m1, S, n_rows, ntot, NB,
        tab0, W1t, W2t, w3r,
        hcb, nCnt, nPrep, nEmb);

    col_scan<<<NB, 256, 0, stream>>>(hcb, bktCnt, nCnt);

    scan_tiny<<<1, 256, 0, stream>>>(bktCnt, bktBase, NB);

    bin_scatter<<<nCnt, 256, 0, stream>>>(
        ui1_idx, ui1_val, ui0_idx, ui0_val, iu1_idx, iu1_val, iu0_idx, iu0_val,
        n1, n0, m1, m0, S, bktBase, hcb, nCnt, recPacked, recRow, ntot, NB);

    row_hist<<<dim3(NB, YSPLIT), 256, 0, stream>>>(recRow, bktBase, hseg);

    row_sort2<<<dim3(NB, YSPLIT), 256, 0, stream>>>(recPacked, recRow, bktBase, hseg,
                                                    ptr, edges, n_rows, NB);

    // tab8 lives in recPacked's region (dead after row_sort2, past tabF extent)
    to_fp8<<<(n_rows * KDIM / 16 + 255) / 256, 256, 0, stream>>>(tab0, tab8, n_rows * KDIM);

    pull_spmm<<<(n_rows + 3) / 4, 256, 0, stream>>>(tab0, tab8, ptr, edges,
                                                    tabF, S, n_rows);

    tail_mlp<<<(B + 63) / 64, 256, 0, stream>>>(tabF, discW,
                                                W1t, b1, W2t, b2, w3r, b3,
                                                kn, stu_id, exer_id, out, S, B);
}

// Round 22
// 163.735 us; speedup vs baseline: 1.4914x; 1.0608x over previous
//
#include <hip/hip_runtime.h>

#define KDIM 64
#define NBPAD 512          // padded bucket-array size (NB = 274 here)
#define CHUNK 4096         // records per bin_scatter / count block
#define YSPLIT 8           // row sort segments per bucket

typedef __attribute__((ext_vector_type(8))) short short8v;   // 8 bf16 (4 VGPRs)
typedef __attribute__((ext_vector_type(4))) float f32x4;     // MFMA acc
typedef __attribute__((ext_vector_type(2))) float f32x2;     // fp8 cvt result

__device__ __forceinline__ float bf16u_to_f(unsigned short u) {
    return __uint_as_float(((unsigned)u) << 16);
}
__device__ __forceinline__ float bf16lo(unsigned u) {
    return __uint_as_float(u << 16);
}
__device__ __forceinline__ float bf16hi(unsigned u) {
    return __uint_as_float(u & 0xFFFF0000u);
}
__device__ __forceinline__ unsigned short f_to_bf16u(float f) {
    unsigned b = __float_as_uint(f);
    b += 0x7FFF + ((b >> 16) & 1);          // round-to-nearest-even
    return (unsigned short)(b >> 16);
}
__device__ __forceinline__ unsigned pack2bf16(float lo, float hi) {
    return ((unsigned)f_to_bf16u(lo)) | (((unsigned)f_to_bf16u(hi)) << 16);
}
__device__ __forceinline__ float sigmoidf_(float x) {
    return 1.f / (1.f + __expf(-x));
}

// Unified row space over the 4 concatenated edge lists:
// [0,S) students (ui1,ui0), [S,S+E) exercises (iu1,iu0).
__device__ __forceinline__ int dec_row(int e,
    const int* __restrict__ i1, const int* __restrict__ i0,
    const int* __restrict__ j1, const int* __restrict__ j0,
    int n1, int n0, int m1, int S_)
{
    if (e < n1) return i1[e];
    e -= n1;
    if (e < n0) return i0[e];
    e -= n0;
    if (e < m1) return S_ + j1[e];
    e -= m1;
    return S_ + j0[e];
}

__device__ __forceinline__ void dec_full(int e,
    const int* __restrict__ i1, const float* __restrict__ v1,
    const int* __restrict__ i0, const float* __restrict__ v0,
    const int* __restrict__ j1, const float* __restrict__ w1,
    const int* __restrict__ j0, const float* __restrict__ w0,
    int n1, int n0, int m1, int m0, int S_,
    unsigned& row, unsigned& pk)
{
    int col; float v;
    if (e < n1) { row = (unsigned)i1[e]; col = i1[n1 + e]; v = v1[e]; }
    else if (e < n1 + n0) { int le = e - n1; row = (unsigned)i0[le]; col = i0[n0 + le]; v = v0[le]; }
    else if (e < n1 + n0 + m1) { int le = e - n1 - n0; row = (unsigned)(S_ + j1[le]); col = j1[m1 + le]; v = w1[le]; }
    else { int le = e - n1 - n0 - m1; row = (unsigned)(S_ + j0[le]); col = j0[m0 + le]; v = w0[le]; }
    pk = ((unsigned)col << 16) | (unsigned)f_to_bf16u(v);
}

// -------- front_fused: [prep weights | embed MFMA | per-chunk bucket hist]
// Three independent roles by blockIdx range; NO global atomics anywhere.
__global__ __launch_bounds__(256) void front_fused(
    const float* __restrict__ stuW, const float* __restrict__ exerW,
    const float* __restrict__ knowW,
    const float* __restrict__ W1, const float* __restrict__ W2,
    const float* __restrict__ W3,
    const int* __restrict__ i1, const int* __restrict__ i0,
    const int* __restrict__ j1, const int* __restrict__ j0,
    int n1, int n0, int m1, int S_, int n_rows, int ntot, int NB,
    unsigned short* __restrict__ tab0,
    unsigned short* __restrict__ W1t, unsigned short* __restrict__ W2t,
    float* __restrict__ w3r,
    int* __restrict__ hcb, int nCnt,
    int nPrep, int nEmb)
{
    __shared__ int shmem[NBPAD];
    const int tid = threadIdx.x;
    int bx = blockIdx.x;

    // ---------------- role 1: weight prep (W1t/W2t/w3r) ----------------
    if (bx < nPrep) {
        int i = bx * 256 + tid;
        if (i < 256 * 64) {                     // W1t[n][k] = relu(W1[k][n])
            int n = i >> 6, k = i & 63;
            W1t[i] = f_to_bf16u(fmaxf(W1[k * 256 + n], 0.f));
            return;
        }
        int j = i - 256 * 64;
        if (j < 128 * 256) {                    // W2t[n][k] = relu(W2[k][n])
            int n = j >> 8, k = j & 255;
            W2t[j] = f_to_bf16u(fmaxf(W2[k * 128 + n], 0.f));
            return;
        }
        int l = j - 128 * 256;
        if (l < 128) w3r[l] = fmaxf(W3[l], 0.f);
        return;
    }
    bx -= nPrep;

    // ---------------- role 2: embed MFMA (64 rows/block) ----------------
    if (bx < nEmb) {
        const int w = tid >> 6, l = tid & 63;
        const int lr = l & 15, lg = l >> 4;
        const int r0 = bx * 64 + 16 * w;

        const int arow = min(r0 + lr, n_rows - 1);
        const float* a = (arow < S_) ? (stuW + (size_t)arow * KDIM)
                                     : (exerW + (size_t)(arow - S_) * KDIM);
        float4 v0 = *((const float4*)(a + lg * 8));
        float4 v1 = *((const float4*)(a + lg * 8 + 4));
        float4 v2 = *((const float4*)(a + 32 + lg * 8));
        float4 v3 = *((const float4*)(a + 32 + lg * 8 + 4));
        union { unsigned u[4]; short8v s; } A0, A1;
        A0.u[0] = pack2bf16(v0.x, v0.y); A0.u[1] = pack2bf16(v0.z, v0.w);
        A0.u[2] = pack2bf16(v1.x, v1.y); A0.u[3] = pack2bf16(v1.z, v1.w);
        A1.u[0] = pack2bf16(v2.x, v2.y); A1.u[1] = pack2bf16(v2.z, v2.w);
        A1.u[2] = pack2bf16(v3.x, v3.y); A1.u[3] = pack2bf16(v3.z, v3.w);

        #pragma unroll
        for (int n = 0; n < 4; ++n) {
            const float* kb = knowW + (size_t)(n * 16 + lr) * KDIM + lg * 8;
            float4 b0f = *(const float4*)kb;
            float4 b0g = *(const float4*)(kb + 4);
            float4 b1f = *(const float4*)(kb + 32);
            float4 b1g = *(const float4*)(kb + 36);
            union { unsigned u[4]; short8v s; } B0, B1;
            B0.u[0] = pack2bf16(b0f.x, b0f.y); B0.u[1] = pack2bf16(b0f.z, b0f.w);
            B0.u[2] = pack2bf16(b0g.x, b0g.y); B0.u[3] = pack2bf16(b0g.z, b0g.w);
            B1.u[0] = pack2bf16(b1f.x, b1f.y); B1.u[1] = pack2bf16(b1f.z, b1f.w);
            B1.u[2] = pack2bf16(b1g.x, b1g.y); B1.u[3] = pack2bf16(b1g.z, b1g.w);
            f32x4 acc = {0.f, 0.f, 0.f, 0.f};
            acc = __builtin_amdgcn_mfma_f32_16x16x32_bf16(A0.s, B0.s, acc, 0, 0, 0);
            acc = __builtin_amdgcn_mfma_f32_16x16x32_bf16(A1.s, B1.s, acc, 0, 0, 0);
            #pragma unroll
            for (int q = 0; q < 4; ++q) {
                int srow = r0 + lg * 4 + q;
                if (srow < n_rows)
                    tab0[(size_t)srow * KDIM + n * 16 + lr] = f_to_bf16u(sigmoidf_(acc[q]));
            }
        }
        return;
    }
    bx -= nEmb;

    // ---------------- role 3: per-chunk bucket histogram ----------------
    for (int i = tid; i < NBPAD; i += 256) shmem[i] = 0;
    __syncthreads();
    const int e0 = bx * CHUNK;
    #pragma unroll
    for (int it = 0; it < 16; ++it) {
        int e = e0 + it * 256 + tid;
        if (e < ntot) atomicAdd(&shmem[dec_row(e, i1, i0, j1, j0, n1, n0, m1, S_) >> 8], 1);
    }
    __syncthreads();
    for (int b = tid; b < NB; b += 256)
        hcb[(size_t)b * nCnt + bx] = shmem[b];     // plain store, no atomics
}

// -------- col_scan: per bucket b, exclusive prefix over chunks (in place);
// total -> bktCnt[b]. Contiguous row reads; 274 blocks.
__global__ __launch_bounds__(256) void col_scan(
    int* __restrict__ hcb, int* __restrict__ bktCnt, int nCnt)
{
    __shared__ int sc[256];
    const int b = blockIdx.x, tid = threadIdx.x;
    int* row = hcb + (size_t)b * nCnt;
    int carry = 0;
    for (int t0 = 0; t0 < nCnt; t0 += 256) {
        int idx = t0 + tid;
        int v = (idx < nCnt) ? row[idx] : 0;
        sc[tid] = v;
        __syncthreads();
        for (int o = 1; o < 256; o <<= 1) {
            int a = (tid >= o) ? sc[tid - o] : 0;
            __syncthreads();
            sc[tid] += a;
            __syncthreads();
        }
        if (idx < nCnt) row[idx] = carry + sc[tid] - v;   // exclusive
        carry += sc[255];
        __syncthreads();
    }
    if (tid == 0) bktCnt[b] = carry;
}

// -------- exclusive scan of NB bucket counts -> bktBase
__global__ __launch_bounds__(256) void scan_tiny(
    const int* __restrict__ bktCnt, int* __restrict__ bktBase, int NB)
{
    __shared__ int s[NBPAD + 1];
    for (int i = threadIdx.x; i < NB; i += 256) s[i] = bktCnt[i];
    __syncthreads();
    if (threadIdx.x == 0) {
        int acc = 0;
        for (int b = 0; b < NB; ++b) { int c = s[b]; s[b] = acc; acc += c; }
        s[NB] = acc;
    }
    __syncthreads();
    for (int i = threadIdx.x; i <= NB; i += 256) bktBase[i] = s[i];
}

// -------- binned scatter v5: NO global atomics — gdst from precomputed
// deterministic chunk offsets (bktBase[b] + hcb[b][bx]). Single LDS atomic
// per record (hist return value = slot), shfl 512-prefix.
__global__ __launch_bounds__(256) void bin_scatter(
    const int* __restrict__ i1, const float* __restrict__ v1,
    const int* __restrict__ i0, const float* __restrict__ v0,
    const int* __restrict__ j1, const float* __restrict__ w1,
    const int* __restrict__ j0, const float* __restrict__ w0,
    int n1, int n0, int m1, int m0, int S_,
    const int* __restrict__ bktBase, const int* __restrict__ hcb, int nCnt,
    unsigned* __restrict__ recPacked, unsigned char* __restrict__ recRow,
    int ntot, int NB)
{
    __shared__ int h[NBPAD], sstart[NBPAD], gdst[NBPAD];
    __shared__ int wsum[8];
    __shared__ unsigned stageP[CHUNK];
    __shared__ unsigned stageG[CHUNK];       // (bkt<<8)|rowLocal
    const int tid = threadIdx.x;
    const int bx = blockIdx.x;
    const int e0 = bx * CHUNK;

    for (int i = tid; i < NBPAD; i += 256) h[i] = 0;
    // deterministic global destinations (no atomics) — issue loads early
    if (tid < NB) gdst[tid] = bktBase[tid] + hcb[(size_t)tid * nCnt + bx];
    if (tid + 256 < NB) gdst[tid + 256] = bktBase[tid + 256] + hcb[(size_t)(tid + 256) * nCnt + bx];
    __syncthreads();

    unsigned rrow[16], rpk[16];
    unsigned short rslot[16];
    #pragma unroll
    for (int it = 0; it < 16; ++it) {
        int e = e0 + it * 256 + tid;
        if (e < ntot) {
            dec_full(e, i1, v1, i0, v0, j1, w1, j0, w0, n1, n0, m1, m0, S_,
                     rrow[it], rpk[it]);
            rslot[it] = (unsigned short)atomicAdd(&h[rrow[it] >> 8], 1);
        } else {
            rrow[it] = 0xFFFFFFFFu;
        }
    }
    __syncthreads();

    {   // exclusive prefix over 512 buckets: per-wave shfl scans, one exchange.
        const int wv = tid >> 6, ln = tid & 63;
        int v0h = h[tid];
        int v1h = h[tid + 256];
        int s0 = v0h, s1 = v1h;
        #pragma unroll
        for (int o = 1; o < 64; o <<= 1) {
            int t0 = __shfl_up(s0, o);
            int t1 = __shfl_up(s1, o);
            if (ln >= o) { s0 += t0; s1 += t1; }
        }
        if (ln == 63) { wsum[wv] = s0; wsum[4 + wv] = s1; }
        __syncthreads();
        int woff0 = 0, total0 = 0, woff1lo = 0;
        #pragma unroll
        for (int i = 0; i < 4; ++i) {
            int wl = wsum[i], wh = wsum[4 + i];
            total0 += wl;
            if (i < wv) { woff0 += wl; woff1lo += wh; }
        }
        sstart[tid] = woff0 + s0 - v0h;
        sstart[tid + 256] = total0 + woff1lo + s1 - v1h;
    }
    __syncthreads();

    #pragma unroll
    for (int it = 0; it < 16; ++it) {
        if (rrow[it] != 0xFFFFFFFFu) {
            int slot = sstart[rrow[it] >> 8] + (int)rslot[it];   // no atomics
            stageP[slot] = rpk[it];
            stageG[slot] = rrow[it];
        }
    }
    __syncthreads();

    int cnt = ntot - e0; if (cnt > CHUNK) cnt = CHUNK;
    for (int i = tid; i < cnt; i += 256) {
        unsigned gr = stageG[i];
        int bkt = gr >> 8;
        int dst = gdst[bkt] + (i - sstart[bkt]);
        recPacked[dst] = stageP[i];
        recRow[dst]   = (unsigned char)(gr & 255u);
    }
}

// -------- row_hist: block (b,y) histograms ONLY its segment -> hseg[b][y][256].
__global__ __launch_bounds__(256) void row_hist(
    const unsigned char* __restrict__ recRow, const int* __restrict__ bktBase,
    int* __restrict__ hseg)
{
    __shared__ int h[256];
    const int b = blockIdx.x, y = blockIdx.y, tid = threadIdx.x;
    const int start = bktBase[b], end = bktBase[b + 1];
    const int seg = (end - start + YSPLIT - 1) / YSPLIT;
    int myS = start + y * seg;  if (myS > end) myS = end;
    int myE = myS + seg;        if (myE > end) myE = end;

    h[tid] = 0;
    __syncthreads();
    for (int i = myS + tid; i < myE; i += 256)
        atomicAdd(&h[(int)recRow[i]], 1);
    __syncthreads();
    hseg[((size_t)b * YSPLIT + y) * 256 + tid] = h[tid];
}

// -------- row_sort2 (XCD-affine 1D grid): id = y*NBP8 + b so id%8 == b%8 —
// all YSPLIT segment-blocks of bucket b land on the SAME XCD; the bucket's
// ~58 KB destination window stays in one L2 and lines fill completely
// (round-21 counter: 4.8x write amplification from 4-XCD spread).
__global__ __launch_bounds__(256) void row_sort2(
    const unsigned* __restrict__ recPacked, const unsigned char* __restrict__ recRow,
    const int* __restrict__ bktBase, const int* __restrict__ hseg,
    int* __restrict__ ptr, unsigned* __restrict__ edges, int n_rows, int NB,
    int NBP8)
{
    __shared__ int sc[256], cur[256];
    const int b = blockIdx.x % NBP8;
    const int y = blockIdx.x / NBP8;
    const int tid = threadIdx.x;
    if (b >= NB) return;
    const int r0 = b << 8;
    const int start = bktBase[b], end = bktBase[b + 1];
    const int seg = (end - start + YSPLIT - 1) / YSPLIT;
    int myS = start + y * seg;  if (myS > end) myS = end;
    int myE = myS + seg;        if (myE > end) myE = end;

    int ht = 0, hb = 0;
    const int* hsb = hseg + (size_t)b * YSPLIT * 256 + tid;
    #pragma unroll
    for (int yy = 0; yy < YSPLIT; ++yy) {
        int v = hsb[yy * 256];
        ht += v;
        hb += (yy < y) ? v : 0;
    }

    sc[tid] = ht;
    __syncthreads();
    for (int o = 1; o < 256; o <<= 1) {
        int add = (tid >= o) ? sc[tid - o] : 0;
        __syncthreads();
        sc[tid] += add;
        __syncthreads();
    }
    const int excl = sc[tid] - ht;

    if (y == 0) {
        int grow = r0 + tid;
        if (grow < n_rows) ptr[grow] = start + excl;
        if (b == NB - 1 && tid == 0) ptr[n_rows] = end;
    }
    cur[tid] = excl + hb;
    __syncthreads();

    for (int i = myS + tid; i < myE; i += 256) {
        unsigned pk = recPacked[i];
        int r = (int)recRow[i];
        int dst = start + atomicAdd(&cur[r], 1);
        edges[dst] = pk;
    }
}

// -------- to_fp8: tab0 (bf16) -> tab8 (fp8 e4m3), 16 elems/thread (vectorized).
__global__ __launch_bounds__(256) void to_fp8(
    const unsigned short* __restrict__ tab0, unsigned char* __restrict__ tab8, int n)
{
    int i = blockIdx.x * 256 + threadIdx.x;
    if (i * 16 >= n) return;
    uint4 a = ((const uint4*)tab0)[i * 2];
    uint4 b = ((const uint4*)tab0)[i * 2 + 1];
    uint4 o;
    int t;
    t = __builtin_amdgcn_cvt_pk_fp8_f32(bf16lo(a.x), bf16hi(a.x), 0, false);
    o.x = (unsigned)__builtin_amdgcn_cvt_pk_fp8_f32(bf16lo(a.y), bf16hi(a.y), t, true);
    t = __builtin_amdgcn_cvt_pk_fp8_f32(bf16lo(a.z), bf16hi(a.z), 0, false);
    o.y = (unsigned)__builtin_amdgcn_cvt_pk_fp8_f32(bf16lo(a.w), bf16hi(a.w), t, true);
    t = __builtin_amdgcn_cvt_pk_fp8_f32(bf16lo(b.x), bf16hi(b.x), 0, false);
    o.z = (unsigned)__builtin_amdgcn_cvt_pk_fp8_f32(bf16lo(b.y), bf16hi(b.y), t, true);
    t = __builtin_amdgcn_cvt_pk_fp8_f32(bf16lo(b.z), bf16hi(b.z), 0, false);
    o.w = (unsigned)__builtin_amdgcn_cvt_pk_fp8_f32(bf16lo(b.w), bf16hi(b.w), t, true);
    ((uint4*)tab8)[i] = o;
}

// -------- Pull SpMM v6: fp8 gather + packed f32x2 accumulation.
// Single fully-unrolled 8-iteration body per 64-edge batch; padded edge
// slots carry u=0 (col 0, val 0 -> adds 0).
__global__ __launch_bounds__(256) void pull_spmm(
    const unsigned short* __restrict__ tab0,
    const unsigned char* __restrict__ tab8,
    const int* __restrict__ ptr, const unsigned* __restrict__ edges,
    unsigned short* __restrict__ tabF, int S_, int n_rows)
{
    const int w = blockIdx.x * 4 + (threadIdx.x >> 6);
    if (w >= n_rows) return;
    const int lane = threadIdx.x & 63;
    const int g = lane >> 3;      // 8 edge-groups
    const int s = lane & 7;       // k-range 8s..8s+7

    const unsigned char* X8 = tab8 + ((w < S_) ? ((size_t)S_ << 6) : (size_t)0)
                                   + (size_t)s * 8;

    f32x2 acc2[4];
    #pragma unroll
    for (int i = 0; i < 4; ++i) acc2[i] = (f32x2){0.f, 0.f};

    int e = ptr[w];
    const int ee = ptr[w + 1];
    int len = ee - e;
    unsigned u = (lane < len) ? edges[e + lane] : 0u;

    while (len > 0) {
        unsigned un = (64 + lane < len) ? edges[e + 64 + lane] : 0u;  // prefetch
        #pragma unroll
        for (int jj = 0; jj < 8; ++jj) {
            unsigned uj = __shfl(u, jj * 8 + g);     // 0-word: col 0, val 0 -> adds 0
            float v = __uint_as_float(uj << 16);     // low 16 = bf16 val
            f32x2 vv = {v, v};
            uint2 xv = *(const uint2*)(X8 + (((size_t)(uj >> 16)) << 6));
            acc2[0] = __builtin_amdgcn_cvt_pk_f32_fp8(xv.x, false) * vv + acc2[0];
            acc2[1] = __builtin_amdgcn_cvt_pk_f32_fp8(xv.x, true)  * vv + acc2[1];
            acc2[2] = __builtin_amdgcn_cvt_pk_f32_fp8(xv.y, false) * vv + acc2[2];
            acc2[3] = __builtin_amdgcn_cvt_pk_f32_fp8(xv.y, true)  * vv + acc2[3];
        }
        u = un;
        e += 64;
        len -= 64;
    }

    #pragma unroll
    for (int i = 0; i < 4; ++i) {
        #pragma unroll
        for (int c = 0; c < 2; ++c) {
            acc2[i][c] += __shfl_xor(acc2[i][c], 8);
            acc2[i][c] += __shfl_xor(acc2[i][c], 16);
            acc2[i][c] += __shfl_xor(acc2[i][c], 32);
        }
    }

    if (g == 0) {
        const uint4 x0 = *(const uint4*)(tab0 + ((size_t)w << 6) + (size_t)s * 8);
        uint4 o;
        o.x = pack2bf16(acc2[0][0] + bf16lo(x0.x), acc2[0][1] + bf16hi(x0.x));
        o.y = pack2bf16(acc2[1][0] + bf16lo(x0.y), acc2[1][1] + bf16hi(x0.y));
        o.z = pack2bf16(acc2[2][0] + bf16lo(x0.z), acc2[2][1] + bf16hi(x0.z));
        o.w = pack2bf16(acc2[3][0] + bf16lo(x0.w), acc2[3][1] + bf16hi(x0.w));
        *(uint4*)(tabF + ((size_t)w << 6) + (size_t)s * 8) = o;
    }
}

// -------- MFMA tail: gather -> GEMM1(64x256x64) -> GEMM2(64x128x256) -> dot.
__global__ __launch_bounds__(256, 1) void tail_mlp(
    const unsigned short* __restrict__ tabF,
    const float* __restrict__ discW,
    const unsigned short* __restrict__ W1t, const float* __restrict__ b1,
    const unsigned short* __restrict__ W2t, const float* __restrict__ b2,
    const float* __restrict__ w3r, const float* __restrict__ b3,
    const float* __restrict__ kn, const int* __restrict__ stu_id,
    const int* __restrict__ exer_id, float* __restrict__ out, int S_, int B)
{
    __shared__ __align__(16) unsigned short xs_bf[64][72];   // 9.0 KB (pad: 2-way banks)
    __shared__ __align__(16) unsigned short h1s[64][264];    // 33.0 KB
    __shared__ __align__(16) unsigned short h2s[64][136];    // 17.0 KB
    __shared__ float b1s[256], b2s[128], w3s[128];
    const int tid = threadIdx.x;
    const int b0 = blockIdx.x * 64;

    b1s[tid] = b1[tid];
    if (tid < 128) { b2s[tid] = b2[tid]; w3s[tid] = w3r[tid]; }

    // ---- phase 0: x = disc*(stat-diff)/3*kn -> bf16 LDS tile (vectorized x4)
    #pragma unroll
    for (int i = 0; i < 4; ++i) {
        int e4 = (i * 256 + tid) * 4;
        int r = e4 >> 6, k0 = e4 & 63;
        int b = b0 + r;
        float4 x4 = make_float4(0.f, 0.f, 0.f, 0.f);
        if (b < B) {
            int sid = stu_id[b], eid = exer_id[b];
            float c = sigmoidf_(discW[eid]) * (1.f / 3.f);
            ushort4 st4 = *((const ushort4*)(tabF + (size_t)sid * 64 + k0));
            ushort4 df4 = *((const ushort4*)(tabF + ((size_t)(S_ + eid)) * 64 + k0));
            float4 kn4 = *((const float4*)(kn + (size_t)b * 64 + k0));
            x4.x = c * (bf16u_to_f(st4.x) - bf16u_to_f(df4.x)) * kn4.x;
            x4.y = c * (bf16u_to_f(st4.y) - bf16u_to_f(df4.y)) * kn4.y;
            x4.z = c * (bf16u_to_f(st4.z) - bf16u_to_f(df4.z)) * kn4.z;
            x4.w = c * (bf16u_to_f(st4.w) - bf16u_to_f(df4.w)) * kn4.w;
        }
        ushort4 xb;
        xb.x = f_to_bf16u(x4.x); xb.y = f_to_bf16u(x4.y);
        xb.z = f_to_bf16u(x4.z); xb.w = f_to_bf16u(x4.w);
        *((ushort4*)&xs_bf[r][k0]) = xb;
    }
    __syncthreads();

    const int w  = tid >> 6;
    const int l  = tid & 63;
    const int lr = l & 15;        // A row / B col / C col
    const int lg = l >> 4;        // k-group (8 contig k each)

    // ---- GEMM1: H1 = sigmoid(X[64x64] @ W1r[64x256] + b1)
    {
        short8v a0 = *(const short8v*)&xs_bf[16 * w + lr][lg * 8];
        short8v a1 = *(const short8v*)&xs_bf[16 * w + lr][32 + lg * 8];
        const unsigned short* w1base = W1t + (size_t)lr * 64 + lg * 8;
        #pragma unroll 4
        for (int n = 0; n < 16; ++n) {
            short8v bb0 = *(const short8v*)(w1base + n * 1024);
            short8v bb1 = *(const short8v*)(w1base + n * 1024 + 32);
            f32x4 acc = {0.f, 0.f, 0.f, 0.f};
            acc = __builtin_amdgcn_mfma_f32_16x16x32_bf16(a0, bb0, acc, 0, 0, 0);
            acc = __builtin_amdgcn_mfma_f32_16x16x32_bf16(a1, bb1, acc, 0, 0, 0);
            int col = n * 16 + lr;
            float bias = b1s[col];
            #pragma unroll
            for (int q = 0; q < 4; ++q)
                h1s[16 * w + lg * 4 + q][col] = f_to_bf16u(sigmoidf_(acc[q] + bias));
        }
    }
    __syncthreads();

    // ---- GEMM2: H2 = sigmoid(H1[64x256] @ W2r[256x128] + b2)
    {
        short8v ak[8];
        #pragma unroll
        for (int kk = 0; kk < 8; ++kk)
            ak[kk] = *(const short8v*)&h1s[16 * w + lr][kk * 32 + lg * 8];
        const unsigned short* w2base = W2t + (size_t)lr * 256 + lg * 8;
        #pragma unroll 2
        for (int n = 0; n < 8; ++n) {
            const unsigned short* bp = w2base + (size_t)n * 16 * 256;
            f32x4 acc = {0.f, 0.f, 0.f, 0.f};
            #pragma unroll
            for (int kk = 0; kk < 8; ++kk) {
                short8v bb = *(const short8v*)(bp + kk * 32);
                acc = __builtin_amdgcn_mfma_f32_16x16x32_bf16(ak[kk], bb, acc, 0, 0, 0);
            }
            int col = n * 16 + lr;
            float bias = b2s[col];
            #pragma unroll
            for (int q = 0; q < 4; ++q)
                h2s[16 * w + lg * 4 + q][col] = f_to_bf16u(sigmoidf_(acc[q] + bias));
        }
    }
    __syncthreads();

    // ---- GEMM3: out = sigmoid(H2 @ w3r + b3)   (64 rows, VALU)
    if (tid < 64) {
        int b = b0 + tid;
        if (b < B) {
            float acc = b3[0];
            const unsigned* h2r = (const unsigned*)&h2s[tid][0];
            #pragma unroll 8
            for (int jj = 0; jj < 64; ++jj) {
                unsigned hv = h2r[jj];
                acc += bf16lo(hv) * w3s[jj * 2 + 0] + bf16hi(hv) * w3s[jj * 2 + 1];
            }
            out[b] = sigmoidf_(acc);
        }
    }
}

extern "C" void kernel_launch(void* const* d_in, const int* in_sizes, int n_in,
                              void* d_out, int out_size, void* d_ws, size_t ws_size,
                              hipStream_t stream) {
    const float* stuW  = (const float*)d_in[0];
    const float* exerW = (const float*)d_in[1];
    const float* knowW = (const float*)d_in[2];
    const float* discW = (const float*)d_in[3];
    const float* W1 = (const float*)d_in[4];
    const float* b1 = (const float*)d_in[5];
    const float* W2 = (const float*)d_in[6];
    const float* b2 = (const float*)d_in[7];
    const float* W3 = (const float*)d_in[8];
    const float* b3 = (const float*)d_in[9];
    const int*   ui1_idx = (const int*)d_in[10];
    const float* ui1_val = (const float*)d_in[11];
    const int*   ui0_idx = (const int*)d_in[12];
    const float* ui0_val = (const float*)d_in[13];
    const int*   iu1_idx = (const int*)d_in[14];
    const float* iu1_val = (const float*)d_in[15];
    const int*   iu0_idx = (const int*)d_in[16];
    const float* iu0_val = (const float*)d_in[17];
    const float* kn      = (const float*)d_in[18];
    const int*   stu_id  = (const int*)d_in[19];
    const int*   exer_id = (const int*)d_in[20];
    float* out = (float*)d_out;

    const int S = in_sizes[0] / KDIM;
    const int E = in_sizes[1] / KDIM;
    const int B = in_sizes[19];
    const int n1 = in_sizes[11], n0 = in_sizes[13];
    const int m1 = in_sizes[15], m0 = in_sizes[17];
    const int ntot = n1 + n0 + m1 + m0;
    const int n_rows = S + E;
    const int NB = (n_rows + 255) / 256;            // 274
    const int NBP8 = (NB + 7) & ~7;                 // 280 (mult of 8 for XCD affinity)
    const int nCnt = (ntot + CHUNK - 1) / CHUNK;    // 977

    const int nPrep = (256 * 64 + 128 * 256 + 128 + 255) / 256;   // 193
    const int nEmb  = (n_rows + 63) / 64;                          // 1094

    char* p = (char*)d_ws;
    unsigned short* tab0 = (unsigned short*)p; p += (size_t)n_rows * KDIM * 2;   // 8.96 MB
    unsigned* edges      = (unsigned*)p;       p += (size_t)ntot * 4;            // 16 MB (final)
    unsigned* recPacked  = (unsigned*)p;                                         // 16 MB (temp)
    // tabF aliases recPacked[0..]; tab8 aliases recPacked after tabF's extent.
    unsigned short* tabF = (unsigned short*)recPacked;
    unsigned char* tab8  = (unsigned char*)recPacked + (size_t)n_rows * KDIM * 2;
    p += (size_t)ntot * 4;
    unsigned char* recRow = (unsigned char*)p; p += (size_t)ntot;                // 4 MB (temp)
    int* ptr    = (int*)p;                     p += (size_t)(n_rows + 1) * 4;
    int* bktCnt = (int*)p;                     p += (size_t)NBPAD * 4;
    int* bktBase= (int*)p;                     p += (size_t)(NBPAD + 1) * 4;
    p = (char*)(((uintptr_t)p + 255) & ~(uintptr_t)255);     // 16B+ align for vec loads
    unsigned short* W1t = (unsigned short*)p;  p += 256 * 64 * 2;                // 32 KB
    unsigned short* W2t = (unsigned short*)p;  p += 128 * 256 * 2;               // 64 KB
    float* w3r          = (float*)p;           p += 128 * 4;
    p = (char*)(((uintptr_t)p + 255) & ~(uintptr_t)255);
    int* hseg           = (int*)p;             p += (size_t)NB * YSPLIT * 256 * 4; // 2.24 MB
    p = (char*)(((uintptr_t)p + 255) & ~(uintptr_t)255);
    int* hcb            = (int*)p;             p += (size_t)NB * nCnt * 4;         // 1.07 MB

    front_fused<<<nPrep + nEmb + nCnt, 256, 0, stream>>>(
        stuW, exerW, knowW, W1, W2, W3,
        ui1_idx, ui0_idx, iu1_idx, iu0_idx,
        n1, n0, m1, S, n_rows, ntot, NB,
        tab0, W1t, W2t, w3r,
        hcb, nCnt, nPrep, nEmb);

    col_scan<<<NB, 256, 0, stream>>>(hcb, bktCnt, nCnt);

    scan_tiny<<<1, 256, 0, stream>>>(bktCnt, bktBase, NB);

    bin_scatter<<<nCnt, 256, 0, stream>>>(
        ui1_idx, ui1_val, ui0_idx, ui0_val, iu1_idx, iu1_val, iu0_idx, iu0_val,
        n1, n0, m1, m0, S, bktBase, hcb, nCnt, recPacked, recRow, ntot, NB);

    row_hist<<<dim3(NB, YSPLIT), 256, 0, stream>>>(recRow, bktBase, hseg);

    row_sort2<<<NBP8 * YSPLIT, 256, 0, stream>>>(recPacked, recRow, bktBase, hseg,
                                                 ptr, edges, n_rows, NB, NBP8);

    // tab8 lives in recPacked's region (dead after row_sort2, past tabF extent)
    to_fp8<<<(n_rows * KDIM / 16 + 255) / 256, 256, 0, stream>>>(tab0, tab8, n_rows * KDIM);

    pull_spmm<<<(n_rows + 3) / 4, 256, 0, stream>>>(tab0, tab8, ptr, edges,
                                                    tabF, S, n_rows);

    tail_mlp<<<(B + 63) / 64, 256, 0, stream>>>(tabF, discW,
                                                W1t, b1, W2t, b2, w3r, b3,
                                                kn, stu_id, exer_id, out, S, B);
}

// Round 23
// 159.279 us; speedup vs baseline: 1.5331x; 1.0280x over previous
//
#include <hip/hip_runtime.h>

#define KDIM 64
#define NBPAD 512          // padded bucket-array size (NB = 274 here)
#define CHUNK 4096         // records per bin_scatter / count block
#define YSPLIT 8           // row sort segments per bucket

typedef __attribute__((ext_vector_type(8))) short short8v;   // 8 bf16 (4 VGPRs)
typedef __attribute__((ext_vector_type(4))) float f32x4;     // MFMA acc
typedef __attribute__((ext_vector_type(2))) float f32x2;     // fp8 cvt result

__device__ __forceinline__ float bf16u_to_f(unsigned short u) {
    return __uint_as_float(((unsigned)u) << 16);
}
__device__ __forceinline__ float bf16lo(unsigned u) {
    return __uint_as_float(u << 16);
}
__device__ __forceinline__ float bf16hi(unsigned u) {
    return __uint_as_float(u & 0xFFFF0000u);
}
__device__ __forceinline__ unsigned short f_to_bf16u(float f) {
    unsigned b = __float_as_uint(f);
    b += 0x7FFF + ((b >> 16) & 1);          // round-to-nearest-even
    return (unsigned short)(b >> 16);
}
__device__ __forceinline__ unsigned pack2bf16(float lo, float hi) {
    return ((unsigned)f_to_bf16u(lo)) | (((unsigned)f_to_bf16u(hi)) << 16);
}
__device__ __forceinline__ float sigmoidf_(float x) {
    return 1.f / (1.f + __expf(-x));
}

// Unified row space over the 4 concatenated edge lists:
// [0,S) students (ui1,ui0), [S,S+E) exercises (iu1,iu0).
__device__ __forceinline__ int dec_row(int e,
    const int* __restrict__ i1, const int* __restrict__ i0,
    const int* __restrict__ j1, const int* __restrict__ j0,
    int n1, int n0, int m1, int S_)
{
    if (e < n1) return i1[e];
    e -= n1;
    if (e < n0) return i0[e];
    e -= n0;
    if (e < m1) return S_ + j1[e];
    e -= m1;
    return S_ + j0[e];
}

__device__ __forceinline__ void dec_full(int e,
    const int* __restrict__ i1, const float* __restrict__ v1,
    const int* __restrict__ i0, const float* __restrict__ v0,
    const int* __restrict__ j1, const float* __restrict__ w1,
    const int* __restrict__ j0, const float* __restrict__ w0,
    int n1, int n0, int m1, int m0, int S_,
    unsigned& row, unsigned& pk)
{
    int col; float v;
    if (e < n1) { row = (unsigned)i1[e]; col = i1[n1 + e]; v = v1[e]; }
    else if (e < n1 + n0) { int le = e - n1; row = (unsigned)i0[le]; col = i0[n0 + le]; v = v0[le]; }
    else if (e < n1 + n0 + m1) { int le = e - n1 - n0; row = (unsigned)(S_ + j1[le]); col = j1[m1 + le]; v = w1[le]; }
    else { int le = e - n1 - n0 - m1; row = (unsigned)(S_ + j0[le]); col = j0[m0 + le]; v = w0[le]; }
    pk = ((unsigned)col << 16) | (unsigned)f_to_bf16u(v);
}

// -------- front_fused: [prep weights | embed MFMA | per-chunk bucket hist]
// Three independent roles by blockIdx range; NO global atomics anywhere.
__global__ __launch_bounds__(256) void front_fused(
    const float* __restrict__ stuW, const float* __restrict__ exerW,
    const float* __restrict__ knowW,
    const float* __restrict__ W1, const float* __restrict__ W2,
    const float* __restrict__ W3,
    const int* __restrict__ i1, const int* __restrict__ i0,
    const int* __restrict__ j1, const int* __restrict__ j0,
    int n1, int n0, int m1, int S_, int n_rows, int ntot, int NB,
    unsigned short* __restrict__ tab0,
    unsigned short* __restrict__ W1t, unsigned short* __restrict__ W2t,
    float* __restrict__ w3r,
    int* __restrict__ hcb, int nCnt,
    int nPrep, int nEmb)
{
    __shared__ int shmem[NBPAD];
    const int tid = threadIdx.x;
    int bx = blockIdx.x;

    // ---------------- role 1: weight prep (W1t/W2t/w3r) ----------------
    if (bx < nPrep) {
        int i = bx * 256 + tid;
        if (i < 256 * 64) {                     // W1t[n][k] = relu(W1[k][n])
            int n = i >> 6, k = i & 63;
            W1t[i] = f_to_bf16u(fmaxf(W1[k * 256 + n], 0.f));
            return;
        }
        int j = i - 256 * 64;
        if (j < 128 * 256) {                    // W2t[n][k] = relu(W2[k][n])
            int n = j >> 8, k = j & 255;
            W2t[j] = f_to_bf16u(fmaxf(W2[k * 128 + n], 0.f));
            return;
        }
        int l = j - 128 * 256;
        if (l < 128) w3r[l] = fmaxf(W3[l], 0.f);
        return;
    }
    bx -= nPrep;

    // ---------------- role 2: embed MFMA (64 rows/block) ----------------
    if (bx < nEmb) {
        const int w = tid >> 6, l = tid & 63;
        const int lr = l & 15, lg = l >> 4;
        const int r0 = bx * 64 + 16 * w;

        const int arow = min(r0 + lr, n_rows - 1);
        const float* a = (arow < S_) ? (stuW + (size_t)arow * KDIM)
                                     : (exerW + (size_t)(arow - S_) * KDIM);
        float4 v0 = *((const float4*)(a + lg * 8));
        float4 v1 = *((const float4*)(a + lg * 8 + 4));
        float4 v2 = *((const float4*)(a + 32 + lg * 8));
        float4 v3 = *((const float4*)(a + 32 + lg * 8 + 4));
        union { unsigned u[4]; short8v s; } A0, A1;
        A0.u[0] = pack2bf16(v0.x, v0.y); A0.u[1] = pack2bf16(v0.z, v0.w);
        A0.u[2] = pack2bf16(v1.x, v1.y); A0.u[3] = pack2bf16(v1.z, v1.w);
        A1.u[0] = pack2bf16(v2.x, v2.y); A1.u[1] = pack2bf16(v2.z, v2.w);
        A1.u[2] = pack2bf16(v3.x, v3.y); A1.u[3] = pack2bf16(v3.z, v3.w);

        #pragma unroll
        for (int n = 0; n < 4; ++n) {
            const float* kb = knowW + (size_t)(n * 16 + lr) * KDIM + lg * 8;
            float4 b0f = *(const float4*)kb;
            float4 b0g = *(const float4*)(kb + 4);
            float4 b1f = *(const float4*)(kb + 32);
            float4 b1g = *(const float4*)(kb + 36);
            union { unsigned u[4]; short8v s; } B0, B1;
            B0.u[0] = pack2bf16(b0f.x, b0f.y); B0.u[1] = pack2bf16(b0f.z, b0f.w);
            B0.u[2] = pack2bf16(b0g.x, b0g.y); B0.u[3] = pack2bf16(b0g.z, b0g.w);
            B1.u[0] = pack2bf16(b1f.x, b1f.y); B1.u[1] = pack2bf16(b1f.z, b1f.w);
            B1.u[2] = pack2bf16(b1g.x, b1g.y); B1.u[3] = pack2bf16(b1g.z, b1g.w);
            f32x4 acc = {0.f, 0.f, 0.f, 0.f};
            acc = __builtin_amdgcn_mfma_f32_16x16x32_bf16(A0.s, B0.s, acc, 0, 0, 0);
            acc = __builtin_amdgcn_mfma_f32_16x16x32_bf16(A1.s, B1.s, acc, 0, 0, 0);
            #pragma unroll
            for (int q = 0; q < 4; ++q) {
                int srow = r0 + lg * 4 + q;
                if (srow < n_rows)
                    tab0[(size_t)srow * KDIM + n * 16 + lr] = f_to_bf16u(sigmoidf_(acc[q]));
            }
        }
        return;
    }
    bx -= nEmb;

    // ---------------- role 3: per-chunk bucket histogram ----------------
    for (int i = tid; i < NBPAD; i += 256) shmem[i] = 0;
    __syncthreads();
    const int e0 = bx * CHUNK;
    #pragma unroll
    for (int it = 0; it < 16; ++it) {
        int e = e0 + it * 256 + tid;
        if (e < ntot) atomicAdd(&shmem[dec_row(e, i1, i0, j1, j0, n1, n0, m1, S_) >> 8], 1);
    }
    __syncthreads();
    for (int b = tid; b < NB; b += 256)
        hcb[(size_t)b * nCnt + bx] = shmem[b];     // plain store, no atomics
}

// -------- scan_fp8: [col_scan over chunks (shfl-based) | to_fp8 convert] —
// two independent roles fused into one launch (both depend only on front_fused).
__global__ __launch_bounds__(256) void scan_fp8(
    int* __restrict__ hcb, int* __restrict__ bktCnt, int nCnt, int NB,
    const unsigned short* __restrict__ tab0, unsigned char* __restrict__ tab8,
    int ntab)
{
    int bx = blockIdx.x;
    const int tid = threadIdx.x;

    if (bx < NB) {
        // ---- role 1: exclusive prefix of hcb[b][*] over chunks; total -> bktCnt
        __shared__ int wsum[4];
        const int wv = tid >> 6, ln = tid & 63;
        int* row = hcb + (size_t)bx * nCnt;
        int carry = 0;
        for (int t0 = 0; t0 < nCnt; t0 += 256) {
            int idx = t0 + tid;
            int v = (idx < nCnt) ? row[idx] : 0;
            int s = v;
            #pragma unroll
            for (int o = 1; o < 64; o <<= 1) {
                int t = __shfl_up(s, o);
                if (ln >= o) s += t;
            }
            if (ln == 63) wsum[wv] = s;
            __syncthreads();
            int woff = 0, tot = 0;
            #pragma unroll
            for (int i = 0; i < 4; ++i) {
                int wl = wsum[i];
                tot += wl;
                if (i < wv) woff += wl;
            }
            if (idx < nCnt) row[idx] = carry + woff + s - v;   // exclusive
            carry += tot;
            __syncthreads();     // wsum reuse fence
        }
        if (tid == 0) bktCnt[bx] = carry;
        return;
    }
    bx -= NB;

    // ---- role 2: tab0 (bf16) -> tab8 (fp8 e4m3), 16 elems/thread
    int i = bx * 256 + tid;
    if (i * 16 >= ntab) return;
    uint4 a = ((const uint4*)tab0)[i * 2];
    uint4 b = ((const uint4*)tab0)[i * 2 + 1];
    uint4 o;
    int t;
    t = __builtin_amdgcn_cvt_pk_fp8_f32(bf16lo(a.x), bf16hi(a.x), 0, false);
    o.x = (unsigned)__builtin_amdgcn_cvt_pk_fp8_f32(bf16lo(a.y), bf16hi(a.y), t, true);
    t = __builtin_amdgcn_cvt_pk_fp8_f32(bf16lo(a.z), bf16hi(a.z), 0, false);
    o.y = (unsigned)__builtin_amdgcn_cvt_pk_fp8_f32(bf16lo(a.w), bf16hi(a.w), t, true);
    t = __builtin_amdgcn_cvt_pk_fp8_f32(bf16lo(b.x), bf16hi(b.x), 0, false);
    o.z = (unsigned)__builtin_amdgcn_cvt_pk_fp8_f32(bf16lo(b.y), bf16hi(b.y), t, true);
    t = __builtin_amdgcn_cvt_pk_fp8_f32(bf16lo(b.z), bf16hi(b.z), 0, false);
    o.w = (unsigned)__builtin_amdgcn_cvt_pk_fp8_f32(bf16lo(b.w), bf16hi(b.w), t, true);
    ((uint4*)tab8)[i] = o;
}

// -------- exclusive scan of NB bucket counts -> bktBase
__global__ __launch_bounds__(256) void scan_tiny(
    const int* __restrict__ bktCnt, int* __restrict__ bktBase, int NB)
{
    __shared__ int s[NBPAD + 1];
    for (int i = threadIdx.x; i < NB; i += 256) s[i] = bktCnt[i];
    __syncthreads();
    if (threadIdx.x == 0) {
        int acc = 0;
        for (int b = 0; b < NB; ++b) { int c = s[b]; s[b] = acc; acc += c; }
        s[NB] = acc;
    }
    __syncthreads();
    for (int i = threadIdx.x; i <= NB; i += 256) bktBase[i] = s[i];
}

// -------- binned scatter v5: NO global atomics — gdst from precomputed
// deterministic chunk offsets (bktBase[b] + hcb[b][bx]). Single LDS atomic
// per record (hist return value = slot), shfl 512-prefix.
__global__ __launch_bounds__(256) void bin_scatter(
    const int* __restrict__ i1, const float* __restrict__ v1,
    const int* __restrict__ i0, const float* __restrict__ v0,
    const int* __restrict__ j1, const float* __restrict__ w1,
    const int* __restrict__ j0, const float* __restrict__ w0,
    int n1, int n0, int m1, int m0, int S_,
    const int* __restrict__ bktBase, const int* __restrict__ hcb, int nCnt,
    unsigned* __restrict__ recPacked, unsigned char* __restrict__ recRow,
    int ntot, int NB)
{
    __shared__ int h[NBPAD], sstart[NBPAD], gdst[NBPAD];
    __shared__ int wsum[8];
    __shared__ unsigned stageP[CHUNK];
    __shared__ unsigned stageG[CHUNK];       // (bkt<<8)|rowLocal
    const int tid = threadIdx.x;
    const int bx = blockIdx.x;
    const int e0 = bx * CHUNK;

    for (int i = tid; i < NBPAD; i += 256) h[i] = 0;
    // deterministic global destinations (no atomics) — issue loads early
    if (tid < NB) gdst[tid] = bktBase[tid] + hcb[(size_t)tid * nCnt + bx];
    if (tid + 256 < NB) gdst[tid + 256] = bktBase[tid + 256] + hcb[(size_t)(tid + 256) * nCnt + bx];
    __syncthreads();

    unsigned rrow[16], rpk[16];
    unsigned short rslot[16];
    #pragma unroll
    for (int it = 0; it < 16; ++it) {
        int e = e0 + it * 256 + tid;
        if (e < ntot) {
            dec_full(e, i1, v1, i0, v0, j1, w1, j0, w0, n1, n0, m1, m0, S_,
                     rrow[it], rpk[it]);
            rslot[it] = (unsigned short)atomicAdd(&h[rrow[it] >> 8], 1);
        } else {
            rrow[it] = 0xFFFFFFFFu;
        }
    }
    __syncthreads();

    {   // exclusive prefix over 512 buckets: per-wave shfl scans, one exchange.
        const int wv = tid >> 6, ln = tid & 63;
        int v0h = h[tid];
        int v1h = h[tid + 256];
        int s0 = v0h, s1 = v1h;
        #pragma unroll
        for (int o = 1; o < 64; o <<= 1) {
            int t0 = __shfl_up(s0, o);
            int t1 = __shfl_up(s1, o);
            if (ln >= o) { s0 += t0; s1 += t1; }
        }
        if (ln == 63) { wsum[wv] = s0; wsum[4 + wv] = s1; }
        __syncthreads();
        int woff0 = 0, total0 = 0, woff1lo = 0;
        #pragma unroll
        for (int i = 0; i < 4; ++i) {
            int wl = wsum[i], wh = wsum[4 + i];
            total0 += wl;
            if (i < wv) { woff0 += wl; woff1lo += wh; }
        }
        sstart[tid] = woff0 + s0 - v0h;
        sstart[tid + 256] = total0 + woff1lo + s1 - v1h;
    }
    __syncthreads();

    #pragma unroll
    for (int it = 0; it < 16; ++it) {
        if (rrow[it] != 0xFFFFFFFFu) {
            int slot = sstart[rrow[it] >> 8] + (int)rslot[it];   // no atomics
            stageP[slot] = rpk[it];
            stageG[slot] = rrow[it];
        }
    }
    __syncthreads();

    int cnt = ntot - e0; if (cnt > CHUNK) cnt = CHUNK;
    for (int i = tid; i < cnt; i += 256) {
        unsigned gr = stageG[i];
        int bkt = gr >> 8;
        int dst = gdst[bkt] + (i - sstart[bkt]);
        recPacked[dst] = stageP[i];
        recRow[dst]   = (unsigned char)(gr & 255u);
    }
}

// -------- row_hist: block (b,y) histograms ONLY its segment -> hseg[b][y][256].
__global__ __launch_bounds__(256) void row_hist(
    const unsigned char* __restrict__ recRow, const int* __restrict__ bktBase,
    int* __restrict__ hseg)
{
    __shared__ int h[256];
    const int b = blockIdx.x, y = blockIdx.y, tid = threadIdx.x;
    const int start = bktBase[b], end = bktBase[b + 1];
    const int seg = (end - start + YSPLIT - 1) / YSPLIT;
    int myS = start + y * seg;  if (myS > end) myS = end;
    int myE = myS + seg;        if (myE > end) myE = end;

    h[tid] = 0;
    __syncthreads();
    for (int i = myS + tid; i < myE; i += 256)
        atomicAdd(&h[(int)recRow[i]], 1);
    __syncthreads();
    hseg[((size_t)b * YSPLIT + y) * 256 + tid] = h[tid];
}

// -------- row_sort2 (XCD-affine 1D grid): id = y*NBP8 + b so id%8 == b%8 —
// all YSPLIT segment-blocks of bucket b land on the SAME XCD; the bucket's
// ~58 KB destination window stays in one L2 and lines fill completely.
__global__ __launch_bounds__(256) void row_sort2(
    const unsigned* __restrict__ recPacked, const unsigned char* __restrict__ recRow,
    const int* __restrict__ bktBase, const int* __restrict__ hseg,
    int* __restrict__ ptr, unsigned* __restrict__ edges, int n_rows, int NB,
    int NBP8)
{
    __shared__ int sc[256], cur[256];
    const int b = blockIdx.x % NBP8;
    const int y = blockIdx.x / NBP8;
    const int tid = threadIdx.x;
    if (b >= NB) return;
    const int r0 = b << 8;
    const int start = bktBase[b], end = bktBase[b + 1];
    const int seg = (end - start + YSPLIT - 1) / YSPLIT;
    int myS = start + y * seg;  if (myS > end) myS = end;
    int myE = myS + seg;        if (myE > end) myE = end;

    int ht = 0, hb = 0;
    const int* hsb = hseg + (size_t)b * YSPLIT * 256 + tid;
    #pragma unroll
    for (int yy = 0; yy < YSPLIT; ++yy) {
        int v = hsb[yy * 256];
        ht += v;
        hb += (yy < y) ? v : 0;
    }

    sc[tid] = ht;
    __syncthreads();
    for (int o = 1; o < 256; o <<= 1) {
        int add = (tid >= o) ? sc[tid - o] : 0;
        __syncthreads();
        sc[tid] += add;
        __syncthreads();
    }
    const int excl = sc[tid] - ht;

    if (y == 0) {
        int grow = r0 + tid;
        if (grow < n_rows) ptr[grow] = start + excl;
        if (b == NB - 1 && tid == 0) ptr[n_rows] = end;
    }
    cur[tid] = excl + hb;
    __syncthreads();

    for (int i = myS + tid; i < myE; i += 256) {
        unsigned pk = recPacked[i];
        int r = (int)recRow[i];
        int dst = start + atomicAdd(&cur[r], 1);
        edges[dst] = pk;
    }
}

// -------- Pull SpMM v6: fp8 gather + packed f32x2 accumulation.
// Single fully-unrolled 8-iteration body per 64-edge batch; padded edge
// slots carry u=0 (col 0, val 0 -> adds 0).
__global__ __launch_bounds__(256) void pull_spmm(
    const unsigned short* __restrict__ tab0,
    const unsigned char* __restrict__ tab8,
    const int* __restrict__ ptr, const unsigned* __restrict__ edges,
    unsigned short* __restrict__ tabF, int S_, int n_rows)
{
    const int w = blockIdx.x * 4 + (threadIdx.x >> 6);
    if (w >= n_rows) return;
    const int lane = threadIdx.x & 63;
    const int g = lane >> 3;      // 8 edge-groups
    const int s = lane & 7;       // k-range 8s..8s+7

    const unsigned char* X8 = tab8 + ((w < S_) ? ((size_t)S_ << 6) : (size_t)0)
                                   + (size_t)s * 8;

    f32x2 acc2[4];
    #pragma unroll
    for (int i = 0; i < 4; ++i) acc2[i] = (f32x2){0.f, 0.f};

    int e = ptr[w];
    const int ee = ptr[w + 1];
    int len = ee - e;
    unsigned u = (lane < len) ? edges[e + lane] : 0u;

    while (len > 0) {
        unsigned un = (64 + lane < len) ? edges[e + 64 + lane] : 0u;  // prefetch
        #pragma unroll
        for (int jj = 0; jj < 8; ++jj) {
            unsigned uj = __shfl(u, jj * 8 + g);     // 0-word: col 0, val 0 -> adds 0
            float v = __uint_as_float(uj << 16);     // low 16 = bf16 val
            f32x2 vv = {v, v};
            uint2 xv = *(const uint2*)(X8 + (((size_t)(uj >> 16)) << 6));
            acc2[0] = __builtin_amdgcn_cvt_pk_f32_fp8(xv.x, false) * vv + acc2[0];
            acc2[1] = __builtin_amdgcn_cvt_pk_f32_fp8(xv.x, true)  * vv + acc2[1];
            acc2[2] = __builtin_amdgcn_cvt_pk_f32_fp8(xv.y, false) * vv + acc2[2];
            acc2[3] = __builtin_amdgcn_cvt_pk_f32_fp8(xv.y, true)  * vv + acc2[3];
        }
        u = un;
        e += 64;
        len -= 64;
    }

    #pragma unroll
    for (int i = 0; i < 4; ++i) {
        #pragma unroll
        for (int c = 0; c < 2; ++c) {
            acc2[i][c] += __shfl_xor(acc2[i][c], 8);
            acc2[i][c] += __shfl_xor(acc2[i][c], 16);
            acc2[i][c] += __shfl_xor(acc2[i][c], 32);
        }
    }

    if (g == 0) {
        const uint4 x0 = *(const uint4*)(tab0 + ((size_t)w << 6) + (size_t)s * 8);
        uint4 o;
        o.x = pack2bf16(acc2[0][0] + bf16lo(x0.x), acc2[0][1] + bf16hi(x0.x));
        o.y = pack2bf16(acc2[1][0] + bf16lo(x0.y), acc2[1][1] + bf16hi(x0.y));
        o.z = pack2bf16(acc2[2][0] + bf16lo(x0.z), acc2[2][1] + bf16hi(x0.z));
        o.w = pack2bf16(acc2[3][0] + bf16lo(x0.w), acc2[3][1] + bf16hi(x0.w));
        *(uint4*)(tabF + ((size_t)w << 6) + (size_t)s * 8) = o;
    }
}

// -------- MFMA tail: gather -> GEMM1(64x256x64) -> GEMM2(64x128x256) -> dot.
__global__ __launch_bounds__(256, 1) void tail_mlp(
    const unsigned short* __restrict__ tabF,
    const float* __restrict__ discW,
    const unsigned short* __restrict__ W1t, const float* __restrict__ b1,
    const unsigned short* __restrict__ W2t, const float* __restrict__ b2,
    const float* __restrict__ w3r, const float* __restrict__ b3,
    const float* __restrict__ kn, const int* __restrict__ stu_id,
    const int* __restrict__ exer_id, float* __restrict__ out, int S_, int B)
{
    __shared__ __align__(16) unsigned short xs_bf[64][72];   // 9.0 KB (pad: 2-way banks)
    __shared__ __align__(16) unsigned short h1s[64][264];    // 33.0 KB
    __shared__ __align__(16) unsigned short h2s[64][136];    // 17.0 KB
    __shared__ float b1s[256], b2s[128], w3s[128];
    const int tid = threadIdx.x;
    const int b0 = blockIdx.x * 64;

    b1s[tid] = b1[tid];
    if (tid < 128) { b2s[tid] = b2[tid]; w3s[tid] = w3r[tid]; }

    // ---- phase 0: x = disc*(stat-diff)/3*kn -> bf16 LDS tile (vectorized x4)
    #pragma unroll
    for (int i = 0; i < 4; ++i) {
        int e4 = (i * 256 + tid) * 4;
        int r = e4 >> 6, k0 = e4 & 63;
        int b = b0 + r;
        float4 x4 = make_float4(0.f, 0.f, 0.f, 0.f);
        if (b < B) {
            int sid = stu_id[b], eid = exer_id[b];
            float c = sigmoidf_(discW[eid]) * (1.f / 3.f);
            ushort4 st4 = *((const ushort4*)(tabF + (size_t)sid * 64 + k0));
            ushort4 df4 = *((const ushort4*)(tabF + ((size_t)(S_ + eid)) * 64 + k0));
            float4 kn4 = *((const float4*)(kn + (size_t)b * 64 + k0));
            x4.x = c * (bf16u_to_f(st4.x) - bf16u_to_f(df4.x)) * kn4.x;
            x4.y = c * (bf16u_to_f(st4.y) - bf16u_to_f(df4.y)) * kn4.y;
            x4.z = c * (bf16u_to_f(st4.z) - bf16u_to_f(df4.z)) * kn4.z;
            x4.w = c * (bf16u_to_f(st4.w) - bf16u_to_f(df4.w)) * kn4.w;
        }
        ushort4 xb;
        xb.x = f_to_bf16u(x4.x); xb.y = f_to_bf16u(x4.y);
        xb.z = f_to_bf16u(x4.z); xb.w = f_to_bf16u(x4.w);
        *((ushort4*)&xs_bf[r][k0]) = xb;
    }
    __syncthreads();

    const int w  = tid >> 6;
    const int l  = tid & 63;
    const int lr = l & 15;        // A row / B col / C col
    const int lg = l >> 4;        // k-group (8 contig k each)

    // ---- GEMM1: H1 = sigmoid(X[64x64] @ W1r[64x256] + b1)
    {
        short8v a0 = *(const short8v*)&xs_bf[16 * w + lr][lg * 8];
        short8v a1 = *(const short8v*)&xs_bf[16 * w + lr][32 + lg * 8];
        const unsigned short* w1base = W1t + (size_t)lr * 64 + lg * 8;
        #pragma unroll 4
        for (int n = 0; n < 16; ++n) {
            short8v bb0 = *(const short8v*)(w1base + n * 1024);
            short8v bb1 = *(const short8v*)(w1base + n * 1024 + 32);
            f32x4 acc = {0.f, 0.f, 0.f, 0.f};
            acc = __builtin_amdgcn_mfma_f32_16x16x32_bf16(a0, bb0, acc, 0, 0, 0);
            acc = __builtin_amdgcn_mfma_f32_16x16x32_bf16(a1, bb1, acc, 0, 0, 0);
            int col = n * 16 + lr;
            float bias = b1s[col];
            #pragma unroll
            for (int q = 0; q < 4; ++q)
                h1s[16 * w + lg * 4 + q][col] = f_to_bf16u(sigmoidf_(acc[q] + bias));
        }
    }
    __syncthreads();

    // ---- GEMM2: H2 = sigmoid(H1[64x256] @ W2r[256x128] + b2)
    {
        short8v ak[8];
        #pragma unroll
        for (int kk = 0; kk < 8; ++kk)
            ak[kk] = *(const short8v*)&h1s[16 * w + lr][kk * 32 + lg * 8];
        const unsigned short* w2base = W2t + (size_t)lr * 256 + lg * 8;
        #pragma unroll 2
        for (int n = 0; n < 8; ++n) {
            const unsigned short* bp = w2base + (size_t)n * 16 * 256;
            f32x4 acc = {0.f, 0.f, 0.f, 0.f};
            #pragma unroll
            for (int kk = 0; kk < 8; ++kk) {
                short8v bb = *(const short8v*)(bp + kk * 32);
                acc = __builtin_amdgcn_mfma_f32_16x16x32_bf16(ak[kk], bb, acc, 0, 0, 0);
            }
            int col = n * 16 + lr;
            float bias = b2s[col];
            #pragma unroll
            for (int q = 0; q < 4; ++q)
                h2s[16 * w + lg * 4 + q][col] = f_to_bf16u(sigmoidf_(acc[q] + bias));
        }
    }
    __syncthreads();

    // ---- GEMM3: out = sigmoid(H2 @ w3r + b3)   (64 rows, VALU)
    if (tid < 64) {
        int b = b0 + tid;
        if (b < B) {
            float acc = b3[0];
            const unsigned* h2r = (const unsigned*)&h2s[tid][0];
            #pragma unroll 8
            for (int jj = 0; jj < 64; ++jj) {
                unsigned hv = h2r[jj];
                acc += bf16lo(hv) * w3s[jj * 2 + 0] + bf16hi(hv) * w3s[jj * 2 + 1];
            }
            out[b] = sigmoidf_(acc);
        }
    }
}

extern "C" void kernel_launch(void* const* d_in, const int* in_sizes, int n_in,
                              void* d_out, int out_size, void* d_ws, size_t ws_size,
                              hipStream_t stream) {
    const float* stuW  = (const float*)d_in[0];
    const float* exerW = (const float*)d_in[1];
    const float* knowW = (const float*)d_in[2];
    const float* discW = (const float*)d_in[3];
    const float* W1 = (const float*)d_in[4];
    const float* b1 = (const float*)d_in[5];
    const float* W2 = (const float*)d_in[6];
    const float* b2 = (const float*)d_in[7];
    const float* W3 = (const float*)d_in[8];
    const float* b3 = (const float*)d_in[9];
    const int*   ui1_idx = (const int*)d_in[10];
    const float* ui1_val = (const float*)d_in[11];
    const int*   ui0_idx = (const int*)d_in[12];
    const float* ui0_val = (const float*)d_in[13];
    const int*   iu1_idx = (const int*)d_in[14];
    const float* iu1_val = (const float*)d_in[15];
    const int*   iu0_idx = (const int*)d_in[16];
    const float* iu0_val = (const float*)d_in[17];
    const float* kn      = (const float*)d_in[18];
    const int*   stu_id  = (const int*)d_in[19];
    const int*   exer_id = (const int*)d_in[20];
    float* out = (float*)d_out;

    const int S = in_sizes[0] / KDIM;
    const int E = in_sizes[1] / KDIM;
    const int B = in_sizes[19];
    const int n1 = in_sizes[11], n0 = in_sizes[13];
    const int m1 = in_sizes[15], m0 = in_sizes[17];
    const int ntot = n1 + n0 + m1 + m0;
    const int n_rows = S + E;
    const int NB = (n_rows + 255) / 256;            // 274
    const int NBP8 = (NB + 7) & ~7;                 // 280 (mult of 8 for XCD affinity)
    const int nCnt = (ntot + CHUNK - 1) / CHUNK;    // 977
    const int ntab = n_rows * KDIM;

    const int nPrep = (256 * 64 + 128 * 256 + 128 + 255) / 256;   // 193
    const int nEmb  = (n_rows + 63) / 64;                          // 1094
    const int nFp8  = (ntab / 16 + 255) / 256;                     // 1094

    char* p = (char*)d_ws;
    unsigned short* tab0 = (unsigned short*)p; p += (size_t)n_rows * KDIM * 2;   // 8.96 MB
    unsigned* edges      = (unsigned*)p;       p += (size_t)ntot * 4;            // 16 MB (final)
    unsigned* recPacked  = (unsigned*)p;                                         // 16 MB (temp)
    unsigned short* tabF = (unsigned short*)recPacked;   // aliases recPacked (dead by then)
    p += (size_t)ntot * 4;
    unsigned char* recRow = (unsigned char*)p; p += (size_t)ntot;                // 4 MB (temp)
    int* ptr    = (int*)p;                     p += (size_t)(n_rows + 1) * 4;
    int* bktCnt = (int*)p;                     p += (size_t)NBPAD * 4;
    int* bktBase= (int*)p;                     p += (size_t)(NBPAD + 1) * 4;
    p = (char*)(((uintptr_t)p + 255) & ~(uintptr_t)255);     // 16B+ align for vec loads
    unsigned short* W1t = (unsigned short*)p;  p += 256 * 64 * 2;                // 32 KB
    unsigned short* W2t = (unsigned short*)p;  p += 128 * 256 * 2;               // 64 KB
    float* w3r          = (float*)p;           p += 128 * 4;
    p = (char*)(((uintptr_t)p + 255) & ~(uintptr_t)255);
    int* hseg           = (int*)p;             p += (size_t)NB * YSPLIT * 256 * 4; // 2.24 MB
    p = (char*)(((uintptr_t)p + 255) & ~(uintptr_t)255);
    int* hcb            = (int*)p;             p += (size_t)NB * nCnt * 4;         // 1.07 MB
    p = (char*)(((uintptr_t)p + 255) & ~(uintptr_t)255);
    unsigned char* tab8 = (unsigned char*)p;   p += (size_t)ntab;                  // 4.48 MB

    front_fused<<<nPrep + nEmb + nCnt, 256, 0, stream>>>(
        stuW, exerW, knowW, W1, W2, W3,
        ui1_idx, ui0_idx, iu1_idx, iu0_idx,
        n1, n0, m1, S, n_rows, ntot, NB,
        tab0, W1t, W2t, w3r,
        hcb, nCnt, nPrep, nEmb);

    scan_fp8<<<NB + nFp8, 256, 0, stream>>>(hcb, bktCnt, nCnt, NB,
                                            tab0, tab8, ntab);

    scan_tiny<<<1, 256, 0, stream>>>(bktCnt, bktBase, NB);

    bin_scatter<<<nCnt, 256, 0, stream>>>(
        ui1_idx, ui1_val, ui0_idx, ui0_val, iu1_idx, iu1_val, iu0_idx, iu0_val,
        n1, n0, m1, m0, S, bktBase, hcb, nCnt, recPacked, recRow, ntot, NB);

    row_hist<<<dim3(NB, YSPLIT), 256, 0, stream>>>(recRow, bktBase, hseg);

    row_sort2<<<NBP8 * YSPLIT, 256, 0, stream>>>(recPacked, recRow, bktBase, hseg,
                                                 ptr, edges, n_rows, NB, NBP8);

    pull_spmm<<<(n_rows + 3) / 4, 256, 0, stream>>>(tab0, tab8, ptr, edges,
                                                    tabF, S, n_rows);

    tail_mlp<<<(B + 63) / 64, 256, 0, stream>>>(tabF, discW,
                                                W1t, b1, W2t, b2, w3r, b3,
                                                kn, stu_id, exer_id, out, S, B);
}